// Round 2
// baseline (4480.527 us; speedup 1.0000x reference)
//
#include <hip/hip_runtime.h>
#include <math.h>

// ============================================================================
// PatchTST/Autoformer hybrid forward on MI355X (gfx950).
//  - Residual stream X: bf16 [43008, 512] (single buffer).
//  - All matmuls: bf16 MFMA 16x16x32, 64x64 tile, 4 waves.
//  - AutoCorrelation: per-sequence 64x64 Gram (fused tau-reduce -> mean_corr),
//    global top-4, softmax weights, circular weighted gather.
//  - concat@Wf done as dual-A split-K GEMM (no concat buffer).
//  - FFN chunked over M (4 x 10752 rows) to reuse one 44 MB buffer.
//  - Workspace ~217 MB; if ws_size smaller: write zeros (diagnostic fallback).
// ============================================================================

typedef unsigned short u16;
typedef short s16x8 __attribute__((ext_vector_type(8)));
typedef u16 u16x8 __attribute__((ext_vector_type(8)));
typedef float f32x4 __attribute__((ext_vector_type(4)));

#define MROWS 43008   // 672 * 64
#define NSEQ  672
#define DM    512

__device__ __forceinline__ float bf2f(u16 b) {
  union { unsigned u; float f; } v; v.u = ((unsigned)b) << 16; return v.f;
}
__device__ __forceinline__ u16 f2bf(float f) {
  union { float f; unsigned u; } v; v.f = f;
  unsigned r = v.u + 0x7FFFu + ((v.u >> 16) & 1u);
  return (u16)(r >> 16);
}

// ---------------------------------------------------------------- fallback
__global__ __launch_bounds__(256) void zero_out_kernel(float* __restrict__ o, int n) {
  int i = blockIdx.x * 256 + threadIdx.x;
  if (i < n) o[i] = 0.f;
}

// ---------------------------------------------------------------- transpose
// W [K,N] fp32 -> Wt [N,K] bf16
__global__ __launch_bounds__(256) void transpose_cvt(
    const float* __restrict__ W, u16* __restrict__ Wt, int K, int N) {
  __shared__ float t[32][33];
  int k0 = blockIdx.x * 32, n0 = blockIdx.y * 32;
  int tx = threadIdx.x, ty = threadIdx.y;   // 32 x 8
#pragma unroll
  for (int i = 0; i < 32; i += 8)
    t[ty + i][tx] = W[(size_t)(k0 + ty + i) * N + n0 + tx];
  __syncthreads();
#pragma unroll
  for (int i = 0; i < 32; i += 8)
    Wt[(size_t)(n0 + ty + i) * K + k0 + tx] = f2bf(t[tx][ty + i]);
}

// ---------------------------------------------------------------- GEMM core
// C[M,N](bf16) = A[M,K](bf16, row stride lda) @ Bt[N,K](bf16, row stride ldb)^T
//              + bias, optional relu. Grid (M/64, N/64).
__global__ __launch_bounds__(256) void gemm_bf16(
    const u16* __restrict__ A, int lda, const u16* __restrict__ Bt, int ldb,
    const float* __restrict__ bias, u16* __restrict__ C, int N, int K, int relu) {
  __shared__ u16 lA[64][40];
  __shared__ u16 lB[64][40];
  int m0 = blockIdx.x * 64, n0 = blockIdx.y * 64;
  int tid = threadIdx.x, lane = tid & 63, w = tid >> 6;
  int sr = tid >> 2, scol = (tid & 3) * 8;
  f32x4 acc[4];
#pragma unroll
  for (int i = 0; i < 4; i++) acc[i] = (f32x4){0.f, 0.f, 0.f, 0.f};
  const u16* Ar = A + (size_t)(m0 + sr) * lda + scol;
  const u16* Br = Bt + (size_t)(n0 + sr) * ldb + scol;
  for (int k0 = 0; k0 < K; k0 += 32) {
    *(u16x8*)&lA[sr][scol] = *(const u16x8*)(Ar + k0);
    *(u16x8*)&lB[sr][scol] = *(const u16x8*)(Br + k0);
    __syncthreads();
    int ar = w * 16 + (lane & 15);
    int kk = (lane >> 4) * 8;
    s16x8 af = *(const s16x8*)&lA[ar][kk];
#pragma unroll
    for (int nb = 0; nb < 4; nb++) {
      s16x8 bfr = *(const s16x8*)&lB[nb * 16 + (lane & 15)][kk];
      acc[nb] = __builtin_amdgcn_mfma_f32_16x16x32_bf16(af, bfr, acc[nb], 0, 0, 0);
    }
    __syncthreads();
  }
  // C/D layout: col = lane&15, row = (lane>>4)*4 + reg   [m89/m91]
  int rbase = m0 + w * 16 + ((lane >> 4) << 2);
  int cl = lane & 15;
#pragma unroll
  for (int nb = 0; nb < 4; nb++) {
    int col = n0 + nb * 16 + cl;
    float bv = bias ? bias[col] : 0.f;
#pragma unroll
    for (int r = 0; r < 4; r++) {
      float v = acc[nb][r] + bv;
      if (relu) v = fmaxf(v, 0.f);
      C[(size_t)(rbase + r) * N + col] = f2bf(v);
    }
  }
}

// C = A1@Bt[:, :512]^T + A2@Bt[:, 512:]^T + bias.  Bt is [N][1024], A* [M][512].
__global__ __launch_bounds__(256) void gemm_dual(
    const u16* __restrict__ A1, const u16* __restrict__ A2,
    const u16* __restrict__ Bt, const float* __restrict__ bias,
    u16* __restrict__ C, int N) {
  __shared__ u16 lA[64][40];
  __shared__ u16 lB[64][40];
  int m0 = blockIdx.x * 64, n0 = blockIdx.y * 64;
  int tid = threadIdx.x, lane = tid & 63, w = tid >> 6;
  int sr = tid >> 2, scol = (tid & 3) * 8;
  f32x4 acc[4];
#pragma unroll
  for (int i = 0; i < 4; i++) acc[i] = (f32x4){0.f, 0.f, 0.f, 0.f};
  for (int k0 = 0; k0 < 1024; k0 += 32) {
    const u16* Ap = (k0 < 512)
        ? A1 + (size_t)(m0 + sr) * 512 + k0 + scol
        : A2 + (size_t)(m0 + sr) * 512 + (k0 - 512) + scol;
    *(u16x8*)&lA[sr][scol] = *(const u16x8*)Ap;
    *(u16x8*)&lB[sr][scol] = *(const u16x8*)&Bt[(size_t)(n0 + sr) * 1024 + k0 + scol];
    __syncthreads();
    int ar = w * 16 + (lane & 15);
    int kk = (lane >> 4) * 8;
    s16x8 af = *(const s16x8*)&lA[ar][kk];
#pragma unroll
    for (int nb = 0; nb < 4; nb++) {
      s16x8 bfr = *(const s16x8*)&lB[nb * 16 + (lane & 15)][kk];
      acc[nb] = __builtin_amdgcn_mfma_f32_16x16x32_bf16(af, bfr, acc[nb], 0, 0, 0);
    }
    __syncthreads();
  }
  int rbase = m0 + w * 16 + ((lane >> 4) << 2);
  int cl = lane & 15;
#pragma unroll
  for (int nb = 0; nb < 4; nb++) {
    int col = n0 + nb * 16 + cl;
    float bv = bias[col];
#pragma unroll
    for (int r = 0; r < 4; r++)
      C[(size_t)(rbase + r) * N + col] = f2bf(acc[nb][r] + bv);
  }
}

// ---------------------------------------------------------------- gram + mc
// Per sequence n: G[t][s] = sum_d q[t,d]*k[s,d]; MC[n,tau] = sum_t G[t][(t-tau)&63]/512.
__global__ __launch_bounds__(256) void gram_mc_kernel(
    const u16* __restrict__ Q, const u16* __restrict__ K, float* __restrict__ MC) {
  __shared__ u16 lA[64][40];
  __shared__ u16 lB[64][40];
  __shared__ float red[64];
  int n = blockIdx.x;
  int tid = threadIdx.x, lane = tid & 63, w = tid >> 6;
  int sr = tid >> 2, scol = (tid & 3) * 8;
  if (tid < 64) red[tid] = 0.f;
  f32x4 acc[4];
#pragma unroll
  for (int i = 0; i < 4; i++) acc[i] = (f32x4){0.f, 0.f, 0.f, 0.f};
  size_t base = (size_t)n * 64 * 512;
  for (int k0 = 0; k0 < 512; k0 += 32) {
    *(u16x8*)&lA[sr][scol] = *(const u16x8*)&Q[base + (size_t)sr * 512 + k0 + scol];
    *(u16x8*)&lB[sr][scol] = *(const u16x8*)&K[base + (size_t)sr * 512 + k0 + scol];
    __syncthreads();
    int ar = w * 16 + (lane & 15);
    int kk = (lane >> 4) * 8;
    s16x8 af = *(const s16x8*)&lA[ar][kk];
#pragma unroll
    for (int nb = 0; nb < 4; nb++) {
      s16x8 bfr = *(const s16x8*)&lB[nb * 16 + (lane & 15)][kk];
      acc[nb] = __builtin_amdgcn_mfma_f32_16x16x32_bf16(af, bfr, acc[nb], 0, 0, 0);
    }
    __syncthreads();
  }
  int row0 = w * 16 + ((lane >> 4) << 2);
  int cl = lane & 15;
#pragma unroll
  for (int nb = 0; nb < 4; nb++) {
    int col = nb * 16 + cl;
#pragma unroll
    for (int r = 0; r < 4; r++)
      atomicAdd(&red[(row0 + r - col) & 63], acc[nb][r]);
  }
  __syncthreads();
  if (tid < 64) MC[n * 64 + tid] = red[tid] * (1.f / 512.f);
}

// ---------------------------------------------------------------- inst norm
__global__ __launch_bounds__(256) void instnorm_kernel(
    const float* __restrict__ xe, float* __restrict__ MEANS, float* __restrict__ STDEV) {
  int n = blockIdx.x;           // b*21+c
  int b = n / 21, c = n % 21;
  int tid = threadIdx.x;
  float v0 = xe[((size_t)b * 512 + tid) * 21 + c];
  float v1 = xe[((size_t)b * 512 + tid + 256) * 21 + c];
  float s = v0 + v1, ss = v0 * v0 + v1 * v1;
  for (int o = 32; o; o >>= 1) { s += __shfl_down(s, o); ss += __shfl_down(ss, o); }
  __shared__ float rs[4], rss[4];
  if ((tid & 63) == 0) { rs[tid >> 6] = s; rss[tid >> 6] = ss; }
  __syncthreads();
  if (tid == 0) {
    s = rs[0] + rs[1] + rs[2] + rs[3];
    ss = rss[0] + rss[1] + rss[2] + rss[3];
    float mean = s * (1.f / 512.f);
    float var = ss * (1.f / 512.f) - mean * mean;
    MEANS[n] = mean;
    STDEV[n] = sqrtf(var + 1e-5f);
  }
}

// ---------------------------------------------------------------- pos emb
__global__ __launch_bounds__(256) void pe_kernel(float* __restrict__ PE) {
  int i = blockIdx.x * 256 + threadIdx.x;  // 32768
  int p = i >> 9, d = i & 511;
  int k = d >> 1;
  float freq = expf(-(float)(2 * k) * (9.210340371976184f / 512.f));
  float ang = (float)p * freq;
  PE[i] = (d & 1) ? cosf(ang) : sinf(ang);
}

// ---------------------------------------------------------------- patch embed
__global__ __launch_bounds__(256) void patch_kernel(
    const float* __restrict__ xe, const float* __restrict__ wv,
    const float* __restrict__ PE, const float* __restrict__ MEANS,
    const float* __restrict__ STDEV, u16* __restrict__ X) {
  __shared__ float pw[16][512];
  __shared__ float pat[8][16];
  int bx = blockIdx.x;
  int n = bx >> 3, pb = bx & 7;
  int b = n / 21, c = n % 21;
  int tid = threadIdx.x;
  float mean = MEANS[n], inv = 1.f / STDEV[n];
  for (int i = tid; i < 8192; i += 256) pw[i >> 9][i & 511] = wv[i];
  if (tid < 128) {
    int pp = tid >> 4, j = tid & 15;
    int l = (pb * 8 + pp) * 8 + j;
    if (l > 511) l = 511;                       // replication pad
    pat[pp][j] = (xe[((size_t)b * 512 + l) * 21 + c] - mean) * inv;
  }
  __syncthreads();
  for (int i = tid; i < 4096; i += 256) {
    int pp = i >> 9, d = i & 511;
    int p = pb * 8 + pp;
    float s = PE[p * 512 + d];
#pragma unroll
    for (int j = 0; j < 16; j++) s += pat[pp][j] * pw[j][d];
    X[((size_t)n * 64 + p) * 512 + d] = f2bf(s);
  }
}

// ---------------------------------------------------------------- topk / softw
__global__ __launch_bounds__(64) void topk_kernel(
    const float* __restrict__ MC, int* __restrict__ TIDX) {
  __shared__ float g[64];
  int tau = threadIdx.x;
  float s = 0.f;
  for (int n = 0; n < 672; n++) s += MC[n * 64 + tau];
  g[tau] = s;
  __syncthreads();
  if (tau == 0) {
    for (int j = 0; j < 4; j++) {
      int best = 0; float bv = -1e30f;
      for (int t = 0; t < 64; t++) if (g[t] > bv) { bv = g[t]; best = t; }
      TIDX[j] = best;
      g[best] = -1e30f;
    }
  }
}

__global__ __launch_bounds__(256) void softw_kernel(
    const float* __restrict__ MC, const int* __restrict__ TIDX, float* __restrict__ WSM) {
  int n = blockIdx.x * 256 + threadIdx.x;
  if (n >= 672) return;
  float v[4], mx = -1e30f;
#pragma unroll
  for (int j = 0; j < 4; j++) { v[j] = MC[n * 64 + TIDX[j]]; mx = fmaxf(mx, v[j]); }
  float s = 0.f;
#pragma unroll
  for (int j = 0; j < 4; j++) { v[j] = __expf(v[j] - mx); s += v[j]; }
  float inv = 1.f / s;
#pragma unroll
  for (int j = 0; j < 4; j++) WSM[n * 4 + j] = v[j] * inv;
}

// agg[n,l,d] = sum_j w[n,j] * v[n,(l+delay_j)&63,d]
__global__ __launch_bounds__(256) void agg_kernel(
    const u16* __restrict__ V, const float* __restrict__ WSM,
    const int* __restrict__ TIDX, u16* __restrict__ OUT) {
  int n = blockIdx.x;
  __shared__ float w[4];
  __shared__ int dly[4];
  int tid = threadIdx.x;
  if (tid < 4) { w[tid] = WSM[n * 4 + tid]; dly[tid] = TIDX[tid]; }
  __syncthreads();
  for (int i = tid; i < 64 * 512; i += 256) {
    int l = i >> 9, d = i & 511;
    float s = 0.f;
#pragma unroll
    for (int j = 0; j < 4; j++)
      s += w[j] * bf2f(V[((size_t)n * 64 + ((l + dly[j]) & 63)) * 512 + d]);
    OUT[((size_t)n * 64 + l) * 512 + d] = f2bf(s);
  }
}

// ---------------------------------------------------------------- full attention
// per (n,h): 64x64 q,k,v; scores=qk^T/8; softmax; out=Pv -> written over Q.
__global__ __launch_bounds__(256) void attn_kernel(
    u16* __restrict__ Q, const u16* __restrict__ Kb, const u16* __restrict__ Vb) {
  __shared__ u16 lq[64][72], lk[64][72], lv[64][72];
  __shared__ float lp[64][64];                          // [s][l]
  int n = blockIdx.x >> 3, h = blockIdx.x & 7;
  size_t base = ((size_t)n * 64) * 512 + (size_t)h * 64;
  int tid = threadIdx.x;
  int r = tid >> 2, c0 = (tid & 3) * 16;
  *(u16x8*)&lq[r][c0]     = *(const u16x8*)&Q[base + (size_t)r * 512 + c0];
  *(u16x8*)&lq[r][c0 + 8] = *(const u16x8*)&Q[base + (size_t)r * 512 + c0 + 8];
  *(u16x8*)&lk[r][c0]     = *(const u16x8*)&Kb[base + (size_t)r * 512 + c0];
  *(u16x8*)&lk[r][c0 + 8] = *(const u16x8*)&Kb[base + (size_t)r * 512 + c0 + 8];
  *(u16x8*)&lv[r][c0]     = *(const u16x8*)&Vb[base + (size_t)r * 512 + c0];
  *(u16x8*)&lv[r][c0 + 8] = *(const u16x8*)&Vb[base + (size_t)r * 512 + c0 + 8];
  __syncthreads();
  int lane = tid & 63, w = tid >> 6;
  int l = w * 16 + (lane & 15);
  int sq = lane >> 4;
  float sc[16];
#pragma unroll
  for (int j = 0; j < 16; j++) sc[j] = 0.f;
  for (int e0 = 0; e0 < 64; e0 += 8) {
    u16x8 q8 = *(const u16x8*)&lq[l][e0];
    float qv[8];
#pragma unroll
    for (int j = 0; j < 8; j++) qv[j] = bf2f(q8[j]);
#pragma unroll
    for (int s = 0; s < 16; s++) {
      u16x8 k8 = *(const u16x8*)&lk[sq * 16 + s][e0];
#pragma unroll
      for (int j = 0; j < 8; j++) sc[s] += qv[j] * bf2f(k8[j]);
    }
  }
  float mx = -1e30f;
#pragma unroll
  for (int j = 0; j < 16; j++) { sc[j] *= 0.125f; mx = fmaxf(mx, sc[j]); }
  mx = fmaxf(mx, __shfl_xor(mx, 16));
  mx = fmaxf(mx, __shfl_xor(mx, 32));
  float sum = 0.f;
#pragma unroll
  for (int j = 0; j < 16; j++) { sc[j] = __expf(sc[j] - mx); sum += sc[j]; }
  sum += __shfl_xor(sum, 16);
  sum += __shfl_xor(sum, 32);
  float inv = 1.f / sum;
#pragma unroll
  for (int j = 0; j < 16; j++) lp[sq * 16 + j][l] = sc[j] * inv;
  __syncthreads();
  float o[16];
#pragma unroll
  for (int j = 0; j < 16; j++) o[j] = 0.f;
  for (int s = 0; s < 64; s++) {
    float p = lp[s][l];
    u16x8 v0 = *(const u16x8*)&lv[s][sq * 16];
    u16x8 v1 = *(const u16x8*)&lv[s][sq * 16 + 8];
#pragma unroll
    for (int j = 0; j < 8; j++) { o[j] += p * bf2f(v0[j]); o[8 + j] += p * bf2f(v1[j]); }
  }
  u16x8 w0, w1;
#pragma unroll
  for (int j = 0; j < 8; j++) { w0[j] = f2bf(o[j]); w1[j] = f2bf(o[8 + j]); }
  *(u16x8*)&Q[base + (size_t)l * 512 + sq * 16] = w0;
  *(u16x8*)&Q[base + (size_t)l * 512 + sq * 16 + 8] = w1;
}

// ---------------------------------------------------------------- series decomp
// X <- (X + DELTA) - movavg_25_edge_replicated(X + DELTA), per (n,d) over l
__global__ __launch_bounds__(256) void decomp_kernel(
    u16* __restrict__ X, const u16* __restrict__ DELTA) {
  int n = blockIdx.x >> 1;
  int d = ((blockIdx.x & 1) << 8) + threadIdx.x;
  size_t base = ((size_t)n * 64) * 512 + d;
  float v[64];
#pragma unroll
  for (int l = 0; l < 64; l++)
    v[l] = bf2f(X[base + (size_t)l * 512]) + bf2f(DELTA[base + (size_t)l * 512]);
  float s = 12.f * v[0];
#pragma unroll
  for (int t = 0; t <= 12; t++) s += v[t];
#pragma unroll
  for (int l = 0; l < 64; l++) {
    float out = v[l] - s * (1.f / 25.f);
    X[base + (size_t)l * 512] = f2bf(out);
    if (l < 63) {
      int add = l + 13; if (add > 63) add = 63;
      int sub = l - 12; if (sub < 0) sub = 0;
      s += v[add] - v[sub];
    }
  }
}

// ---------------------------------------------------------------- batchnorm
__global__ __launch_bounds__(256) void bn_part(
    const u16* __restrict__ X, float* __restrict__ PS) {
  int ch = blockIdx.x, tid = threadIdx.x;
  float s1a = 0, s2a = 0, s1b = 0, s2b = 0;
  size_t base = (size_t)ch * 128 * 512;
  for (int r = 0; r < 128; r++) {
    float a = bf2f(X[base + (size_t)r * 512 + tid]);
    float b = bf2f(X[base + (size_t)r * 512 + tid + 256]);
    s1a += a; s2a += a * a; s1b += b; s2b += b * b;
  }
  PS[(size_t)(ch * 2 + 0) * 512 + tid] = s1a;
  PS[(size_t)(ch * 2 + 0) * 512 + tid + 256] = s1b;
  PS[(size_t)(ch * 2 + 1) * 512 + tid] = s2a;
  PS[(size_t)(ch * 2 + 1) * 512 + tid + 256] = s2b;
}

__global__ __launch_bounds__(256) void bn_final(
    const float* __restrict__ PS, const float* __restrict__ g,
    const float* __restrict__ b, float* __restrict__ SCALE, float* __restrict__ SHIFT) {
  int d = blockIdx.x * 256 + threadIdx.x;   // < 512
  float s = 0, ss = 0;
  for (int c = 0; c < 336; c++) {
    s += PS[(size_t)(c * 2) * 512 + d];
    ss += PS[(size_t)(c * 2 + 1) * 512 + d];
  }
  float mu = s * (1.f / 43008.f);
  float var = ss * (1.f / 43008.f) - mu * mu;
  float inv = 1.f / sqrtf(var + 1e-5f);
  float sc = g[d] * inv;
  SCALE[d] = sc;
  SHIFT[d] = b[d] - mu * sc;
}

// ---------------------------------------------------------------- head GEMM
// enc[n, d*64+p] = bn(x[n,p,d]); PART[kc][672][96] partial over 16 K-chunks
__global__ __launch_bounds__(256) void head_gemm(
    const u16* __restrict__ X, const float* __restrict__ SCALE,
    const float* __restrict__ SHIFT, const u16* __restrict__ Wht,
    float* __restrict__ PART) {
  __shared__ u16 lA[64][40];
  __shared__ u16 lB[96][40];
  int bm = blockIdx.x;   // 0..10
  int kc = blockIdx.y;   // 0..15
  int tid = threadIdx.x, lane = tid & 63, w = tid >> 6;
  int sr = tid >> 2, sc0 = (tid & 3) * 8;
  f32x4 acc[6];
#pragma unroll
  for (int i = 0; i < 6; i++) acc[i] = (f32x4){0.f, 0.f, 0.f, 0.f};
  for (int kk0 = 0; kk0 < 2048; kk0 += 32) {
    int k0 = kc * 2048 + kk0;
    {
      int n = bm * 64 + sr;
      int k = k0 + sc0;
      int d = k >> 6, p0 = k & 63;
      float scv = SCALE[d], shv = SHIFT[d];
#pragma unroll
      for (int j = 0; j < 8; j++) {
        float xv = (n < 672)
            ? bf2f(X[((size_t)n * 64 + p0 + j) * 512 + d]) * scv + shv : 0.f;
        lA[sr][sc0 + j] = f2bf(xv);
      }
    }
    for (int i = tid; i < 96 * 4; i += 256) {
      int rB = i >> 2, seg = (i & 3) * 8;
      *(u16x8*)&lB[rB][seg] = *(const u16x8*)&Wht[(size_t)rB * 32768 + k0 + seg];
    }
    __syncthreads();
    int ar = w * 16 + (lane & 15);
    int kk = (lane >> 4) * 8;
    s16x8 af = *(const s16x8*)&lA[ar][kk];
#pragma unroll
    for (int nb = 0; nb < 6; nb++) {
      s16x8 bfr = *(const s16x8*)&lB[nb * 16 + (lane & 15)][kk];
      acc[nb] = __builtin_amdgcn_mfma_f32_16x16x32_bf16(af, bfr, acc[nb], 0, 0, 0);
    }
    __syncthreads();
  }
  int rb = bm * 64 + w * 16 + ((lane >> 4) << 2);
  int cl = lane & 15;
#pragma unroll
  for (int nb = 0; nb < 6; nb++) {
    int col = nb * 16 + cl;
#pragma unroll
    for (int r = 0; r < 4; r++) {
      int row = rb + r;
      if (row < 672) PART[((size_t)kc * 672 + row) * 96 + col] = acc[nb][r];
    }
  }
}

__global__ __launch_bounds__(256) void head_reduce(
    const float* __restrict__ PART, const float* __restrict__ bh,
    const float* __restrict__ STDEV, const float* __restrict__ MEANS,
    float* __restrict__ OUT) {
  int i = blockIdx.x * 256 + threadIdx.x;
  if (i >= 672 * 96) return;
  int n = i / 96, r = i % 96;
  float s = bh[r];
  for (int kc = 0; kc < 16; kc++) s += PART[((size_t)kc * 672 + n) * 96 + r];
  int b = n / 21, c = n % 21;
  OUT[((size_t)b * 96 + r) * 21 + c] = s * STDEV[n] + MEANS[n];
}

// ============================================================================
extern "C" void kernel_launch(void* const* d_in, const int* in_sizes, int n_in,
                              void* d_out, int out_size, void* d_ws, size_t ws_size,
                              hipStream_t stream) {
  const float* x_enc = (const float*)d_in[0];
  const float* w_val = (const float*)d_in[1];
  const float* Wq_ac = (const float*)d_in[2];
  const float* Wk_ac = (const float*)d_in[3];
  const float* Wv_ac = (const float*)d_in[4];
  const float* Wo_ac = (const float*)d_in[5];
  const float* bq_ac = (const float*)d_in[6];
  const float* bk_ac = (const float*)d_in[7];
  const float* bv_ac = (const float*)d_in[8];
  const float* bo_ac = (const float*)d_in[9];
  const float* Wq_sa = (const float*)d_in[10];
  const float* Wk_sa = (const float*)d_in[11];
  const float* Wv_sa = (const float*)d_in[12];
  const float* Wo_sa = (const float*)d_in[13];
  const float* bq_sa = (const float*)d_in[14];
  const float* bk_sa = (const float*)d_in[15];
  const float* bv_sa = (const float*)d_in[16];
  const float* bo_sa = (const float*)d_in[17];
  const float* WfW   = (const float*)d_in[18];
  const float* bfW   = (const float*)d_in[19];
  const float* W1    = (const float*)d_in[20];
  const float* W2    = (const float*)d_in[21];
  const float* bn_g  = (const float*)d_in[22];
  const float* bn_b  = (const float*)d_in[23];
  const float* W_head = (const float*)d_in[24];
  const float* b_head = (const float*)d_in[25];
  (void)in_sizes; (void)n_in; (void)out_size;

  // ---- workspace carve-up (~217 MB)
  char* wsp = (char*)d_ws;
  size_t off = 0;
  auto alloc = [&](size_t bytes) -> void* {
    void* p = wsp + off;
    off += (bytes + 255) & ~(size_t)255;
    return p;
  };
  u16* X    = (u16*)alloc((size_t)MROWS * 512 * 2);
  u16* P1   = (u16*)alloc((size_t)MROWS * 512 * 2);
  u16* P2   = (u16*)alloc((size_t)MROWS * 512 * 2);
  u16* P3   = (u16*)alloc((size_t)MROWS * 512 * 2);
  u16* WT   = (u16*)alloc((size_t)17301504 * 2);
  float* PE = (float*)alloc((size_t)32768 * 4);
  float* MEANS = (float*)alloc(672 * 4);
  float* STDEV = (float*)alloc(672 * 4);
  float* MC = (float*)alloc(672 * 64 * 4);
  int* TIDX = (int*)alloc(4 * 4);
  float* WSM = (float*)alloc(672 * 4 * 4);
  float* BNP = (float*)alloc((size_t)336 * 1024 * 4);
  float* SCALE = (float*)alloc(512 * 4);
  float* SHIFT = (float*)alloc(512 * 4);
  float* HEADP = (float*)alloc((size_t)16 * 672 * 96 * 4);

  if (off > ws_size) {
    // Diagnostic fallback: workspace too small -> zeros (absmax will be ~14.3)
    zero_out_kernel<<<252, 256, 0, stream>>>((float*)d_out, 672 * 96);
    return;
  }

  // ---- weight prep: transpose + bf16 convert
  u16* wtp = WT;
  auto tp = [&](const float* src, int K, int N) -> const u16* {
    u16* dst = wtp;
    transpose_cvt<<<dim3(K / 32, N / 32), dim3(32, 8), 0, stream>>>(src, dst, K, N);
    wtp += (size_t)K * N;
    return dst;
  };
  struct LW {
    const u16 *qac, *kac, *vac, *oac, *qsa, *ksa, *vsa, *osa, *wf, *w1, *w2;
  } lw[3];
  for (int l = 0; l < 3; l++) {
    lw[l].qac = tp(Wq_ac + (size_t)l * 262144, 512, 512);
    lw[l].kac = tp(Wk_ac + (size_t)l * 262144, 512, 512);
    lw[l].vac = tp(Wv_ac + (size_t)l * 262144, 512, 512);
    lw[l].oac = tp(Wo_ac + (size_t)l * 262144, 512, 512);
    lw[l].qsa = tp(Wq_sa + (size_t)l * 262144, 512, 512);
    lw[l].ksa = tp(Wk_sa + (size_t)l * 262144, 512, 512);
    lw[l].vsa = tp(Wv_sa + (size_t)l * 262144, 512, 512);
    lw[l].osa = tp(Wo_sa + (size_t)l * 262144, 512, 512);
    lw[l].wf  = tp(WfW   + (size_t)l * 524288, 1024, 512);
    lw[l].w1  = tp(W1    + (size_t)l * 1048576, 512, 2048);
    lw[l].w2  = tp(W2    + (size_t)l * 1048576, 2048, 512);
  }
  const u16* wht = tp(W_head, 32768, 96);

  auto gemm = [&](const u16* A, int lda, const u16* Bt, int ldb, const float* bias,
                  u16* C, int M, int N, int K, int relu) {
    gemm_bf16<<<dim3(M / 64, N / 64), 256, 0, stream>>>(A, lda, Bt, ldb, bias, C, N, K, relu);
  };

  // ---- front end
  instnorm_kernel<<<672, 256, 0, stream>>>(x_enc, MEANS, STDEV);
  pe_kernel<<<128, 256, 0, stream>>>(PE);
  patch_kernel<<<672 * 8, 256, 0, stream>>>(x_enc, w_val, PE, MEANS, STDEV, X);

  // ---- encoder layers
  for (int l = 0; l < 3; l++) {
    const LW& w = lw[l];
    // Self-attention branch (first; leaves s in P2)
    gemm(X, 512, w.qsa, 512, bq_sa + l * 512, P1, MROWS, 512, 512, 0);
    gemm(X, 512, w.ksa, 512, bk_sa + l * 512, P2, MROWS, 512, 512, 0);
    gemm(X, 512, w.vsa, 512, bv_sa + l * 512, P3, MROWS, 512, 512, 0);
    attn_kernel<<<5376, 256, 0, stream>>>(P1, P2, P3);          // out -> P1
    gemm(P1, 512, w.osa, 512, bo_sa + l * 512, P2, MROWS, 512, 512, 0);  // s -> P2
    // AutoCorrelation branch (uses P1,P3; leaves a in P1)
    gemm(X, 512, w.qac, 512, bq_ac + l * 512, P1, MROWS, 512, 512, 0);
    gemm(X, 512, w.kac, 512, bk_ac + l * 512, P3, MROWS, 512, 512, 0);
    gram_mc_kernel<<<672, 256, 0, stream>>>(P1, P3, MC);
    topk_kernel<<<1, 64, 0, stream>>>(MC, TIDX);
    softw_kernel<<<3, 256, 0, stream>>>(MC, TIDX, WSM);
    gemm(X, 512, w.vac, 512, bv_ac + l * 512, P1, MROWS, 512, 512, 0);   // v
    agg_kernel<<<672, 256, 0, stream>>>(P1, WSM, TIDX, P3);
    gemm(P3, 512, w.oac, 512, bo_ac + l * 512, P1, MROWS, 512, 512, 0);  // a -> P1
    // fused = cat(a, s) @ Wf + bf  (dual-A split-K)
    gemm_dual<<<dim3(672, 8), 256, 0, stream>>>(P1, P2, w.wf, bfW + l * 512, P3, 512);
    decomp_kernel<<<1344, 256, 0, stream>>>(X, P3);
    // FFN in 4 M-chunks of 10752 rows (hidden reuses P1: 10752*2048*2 = 44 MB)
    for (int c = 0; c < 4; c++) {
      const u16* Xc = X + (size_t)c * 10752 * 512;
      u16* Yc = P2 + (size_t)c * 10752 * 512;
      gemm(Xc, 512, w.w1, 512, nullptr, P1, 10752, 2048, 512, 1);
      gemm(P1, 2048, w.w2, 2048, nullptr, Yc, 10752, 512, 2048, 0);
    }
    decomp_kernel<<<1344, 256, 0, stream>>>(X, P2);
  }

  // ---- batchnorm + head
  bn_part<<<336, 256, 0, stream>>>(X, BNP);
  bn_final<<<2, 256, 0, stream>>>(BNP, bn_g, bn_b, SCALE, SHIFT);
  head_gemm<<<dim3(11, 16), 256, 0, stream>>>(X, SCALE, SHIFT, wht, HEADP);
  head_reduce<<<252, 256, 0, stream>>>(HEADP, b_head, STDEV, MEANS, (float*)d_out);
}

// Round 3
// 3332.800 us; speedup vs baseline: 1.3444x; 1.3444x over previous
//
#include <hip/hip_runtime.h>
#include <math.h>

// ============================================================================
// PatchTST/Autoformer hybrid forward on MI355X (gfx950).  Round 3.
//  - gemm128: m97-structure GEMM (128x128 tile, BK=32, 4 waves, 4x4 frags,
//    global_load_lds width-16 staging, 2-barrier K-loop). ksplit for concat.
//  - Head: BN+transpose X -> ENC[n][d*64+p] (contiguous), then head GEMM.
//  - AutoCorrelation: per-seq 64x64 Gram fused to mean_corr, top-4, gather.
//  - Residual stream X bf16; FFN M-chunked 4x to fit workspace (~217 MB).
// ============================================================================

typedef unsigned short u16;
typedef short s16x8 __attribute__((ext_vector_type(8)));
typedef u16 u16x8 __attribute__((ext_vector_type(8)));
typedef float f32x4 __attribute__((ext_vector_type(4)));

#define MROWS 43008   // 672 * 64
#define NSEQ  672
#define DM    512

__device__ __forceinline__ float bf2f(u16 b) {
  union { unsigned u; float f; } v; v.u = ((unsigned)b) << 16; return v.f;
}
__device__ __forceinline__ u16 f2bf(float f) {
  union { float f; unsigned u; } v; v.f = f;
  unsigned r = v.u + 0x7FFFu + ((v.u >> 16) & 1u);
  return (u16)(r >> 16);
}

// async global->LDS, 16 B per lane. LDS dest = wave-uniform base + lane*16.
__device__ __forceinline__ void gload16(const u16* g, u16* l) {
  __builtin_amdgcn_global_load_lds(
      (const __attribute__((address_space(1))) unsigned int*)g,
      (__attribute__((address_space(3))) unsigned int*)l, 16, 0, 0);
}

// ---------------------------------------------------------------- fallback
__global__ __launch_bounds__(256) void zero_out_kernel(float* __restrict__ o, int n) {
  int i = blockIdx.x * 256 + threadIdx.x;
  if (i < n) o[i] = 0.f;
}

// ---------------------------------------------------------------- transpose
// W [K,N] fp32 -> Wt [N,K] bf16
__global__ __launch_bounds__(256) void transpose_cvt(
    const float* __restrict__ W, u16* __restrict__ Wt, int K, int N) {
  __shared__ float t[32][33];
  int k0 = blockIdx.x * 32, n0 = blockIdx.y * 32;
  int tx = threadIdx.x, ty = threadIdx.y;   // 32 x 8
#pragma unroll
  for (int i = 0; i < 32; i += 8)
    t[ty + i][tx] = W[(size_t)(k0 + ty + i) * N + n0 + tx];
  __syncthreads();
#pragma unroll
  for (int i = 0; i < 32; i += 8)
    Wt[(size_t)(n0 + ty + i) * K + k0 + tx] = f2bf(t[tx][ty + i]);
}

// ---------------------------------------------------------------- gemm128
// C[M,N](bf16) = A[M,K] @ Bt[N,K]^T + bias, opt relu.
// A rows come from A1 (k < ksplit) else A2 (k - ksplit); both row-stride lda.
// 128x128 tile, BK=32, 256 thr = 4 waves (2x2), global_load_lds staging.
__global__ __launch_bounds__(256) void gemm128(
    const u16* __restrict__ A1, const u16* __restrict__ A2, int lda, int ksplit,
    const u16* __restrict__ Bt, int ldb, const float* __restrict__ bias,
    u16* __restrict__ C, int N, int K, int relu) {
  __shared__ u16 lA[128 * 32];
  __shared__ u16 lB[128 * 32];
  int m0 = blockIdx.x * 128, n0 = blockIdx.y * 128;
  int tid = threadIdx.x, lane = tid & 63, w = tid >> 6;
  int wr = w >> 1, wc = w & 1;
  // staging geometry: inst covers 64 rows (w*16 + lane/4), col (lane&3)*8
  int srow = w * 16 + (lane >> 2);
  int scol = (lane & 3) * 8;
  f32x4 acc[4][4];
#pragma unroll
  for (int i = 0; i < 4; i++)
#pragma unroll
    for (int j = 0; j < 4; j++) acc[i][j] = (f32x4){0.f, 0.f, 0.f, 0.f};
  int m_in = lane & 15;
  int ks = (lane >> 4) * 8;
  for (int k0 = 0; k0 < K; k0 += 32) {
    const u16* Ab;
    int kk;
    if (k0 < ksplit) { Ab = A1; kk = k0; } else { Ab = A2; kk = k0 - ksplit; }
    gload16(&Ab[(size_t)(m0 + srow) * lda + kk + scol],        lA + w * 512);
    gload16(&Ab[(size_t)(m0 + 64 + srow) * lda + kk + scol],   lA + 2048 + w * 512);
    gload16(&Bt[(size_t)(n0 + srow) * ldb + k0 + scol],        lB + w * 512);
    gload16(&Bt[(size_t)(n0 + 64 + srow) * ldb + k0 + scol],   lB + 2048 + w * 512);
    __syncthreads();
    s16x8 a_[4], b_[4];
#pragma unroll
    for (int mf = 0; mf < 4; mf++)
      a_[mf] = *(const s16x8*)&lA[(wr * 64 + mf * 16 + m_in) * 32 + ks];
#pragma unroll
    for (int nf = 0; nf < 4; nf++)
      b_[nf] = *(const s16x8*)&lB[(wc * 64 + nf * 16 + m_in) * 32 + ks];
#pragma unroll
    for (int mf = 0; mf < 4; mf++)
#pragma unroll
      for (int nf = 0; nf < 4; nf++)
        acc[mf][nf] = __builtin_amdgcn_mfma_f32_16x16x32_bf16(
            a_[mf], b_[nf], acc[mf][nf], 0, 0, 0);
    __syncthreads();
  }
  // C/D layout: col = lane&15, row = (lane>>4)*4 + reg   [m89/m91]
  int r0 = m0 + wr * 64 + ((lane >> 4) << 2);
  int cl = lane & 15;
#pragma unroll
  for (int mf = 0; mf < 4; mf++) {
#pragma unroll
    for (int nf = 0; nf < 4; nf++) {
      int col = n0 + wc * 64 + nf * 16 + cl;
      float bv = bias ? bias[col] : 0.f;
#pragma unroll
      for (int r = 0; r < 4; r++) {
        float v = acc[mf][nf][r] + bv;
        if (relu) v = fmaxf(v, 0.f);
        C[(size_t)(r0 + mf * 16 + r) * N + col] = f2bf(v);
      }
    }
  }
}

// ---------------------------------------------------------------- gram + mc
// Per sequence n: G[t][s] = sum_d q[t,d]*k[s,d]; MC[n,tau] = sum_t G[t][(t-tau)&63]/512.
__global__ __launch_bounds__(256) void gram_mc_kernel(
    const u16* __restrict__ Q, const u16* __restrict__ K, float* __restrict__ MC) {
  __shared__ u16 lA[64][40];
  __shared__ u16 lB[64][40];
  __shared__ float red[64];
  int n = blockIdx.x;
  int tid = threadIdx.x, lane = tid & 63, w = tid >> 6;
  int sr = tid >> 2, scol = (tid & 3) * 8;
  if (tid < 64) red[tid] = 0.f;
  f32x4 acc[4];
#pragma unroll
  for (int i = 0; i < 4; i++) acc[i] = (f32x4){0.f, 0.f, 0.f, 0.f};
  size_t base = (size_t)n * 64 * 512;
  for (int k0 = 0; k0 < 512; k0 += 32) {
    *(u16x8*)&lA[sr][scol] = *(const u16x8*)&Q[base + (size_t)sr * 512 + k0 + scol];
    *(u16x8*)&lB[sr][scol] = *(const u16x8*)&K[base + (size_t)sr * 512 + k0 + scol];
    __syncthreads();
    int ar = w * 16 + (lane & 15);
    int kk = (lane >> 4) * 8;
    s16x8 af = *(const s16x8*)&lA[ar][kk];
#pragma unroll
    for (int nb = 0; nb < 4; nb++) {
      s16x8 bfr = *(const s16x8*)&lB[nb * 16 + (lane & 15)][kk];
      acc[nb] = __builtin_amdgcn_mfma_f32_16x16x32_bf16(af, bfr, acc[nb], 0, 0, 0);
    }
    __syncthreads();
  }
  int row0 = w * 16 + ((lane >> 4) << 2);
  int cl = lane & 15;
#pragma unroll
  for (int nb = 0; nb < 4; nb++) {
    int col = nb * 16 + cl;
#pragma unroll
    for (int r = 0; r < 4; r++)
      atomicAdd(&red[(row0 + r - col) & 63], acc[nb][r]);
  }
  __syncthreads();
  if (tid < 64) MC[n * 64 + tid] = red[tid] * (1.f / 512.f);
}

// ---------------------------------------------------------------- inst norm
__global__ __launch_bounds__(256) void instnorm_kernel(
    const float* __restrict__ xe, float* __restrict__ MEANS, float* __restrict__ STDEV) {
  int n = blockIdx.x;           // b*21+c
  int b = n / 21, c = n % 21;
  int tid = threadIdx.x;
  float v0 = xe[((size_t)b * 512 + tid) * 21 + c];
  float v1 = xe[((size_t)b * 512 + tid + 256) * 21 + c];
  float s = v0 + v1, ss = v0 * v0 + v1 * v1;
  for (int o = 32; o; o >>= 1) { s += __shfl_down(s, o); ss += __shfl_down(ss, o); }
  __shared__ float rs[4], rss[4];
  if ((tid & 63) == 0) { rs[tid >> 6] = s; rss[tid >> 6] = ss; }
  __syncthreads();
  if (tid == 0) {
    s = rs[0] + rs[1] + rs[2] + rs[3];
    ss = rss[0] + rss[1] + rss[2] + rss[3];
    float mean = s * (1.f / 512.f);
    float var = ss * (1.f / 512.f) - mean * mean;
    MEANS[n] = mean;
    STDEV[n] = sqrtf(var + 1e-5f);
  }
}

// ---------------------------------------------------------------- pos emb
__global__ __launch_bounds__(256) void pe_kernel(float* __restrict__ PE) {
  int i = blockIdx.x * 256 + threadIdx.x;  // 32768
  int p = i >> 9, d = i & 511;
  int k = d >> 1;
  float freq = expf(-(float)(2 * k) * (9.210340371976184f / 512.f));
  float ang = (float)p * freq;
  PE[i] = (d & 1) ? cosf(ang) : sinf(ang);
}

// ---------------------------------------------------------------- patch embed
__global__ __launch_bounds__(256) void patch_kernel(
    const float* __restrict__ xe, const float* __restrict__ wv,
    const float* __restrict__ PE, const float* __restrict__ MEANS,
    const float* __restrict__ STDEV, u16* __restrict__ X) {
  __shared__ float pw[16][512];
  __shared__ float pat[8][16];
  int bx = blockIdx.x;
  int n = bx >> 3, pb = bx & 7;
  int b = n / 21, c = n % 21;
  int tid = threadIdx.x;
  float mean = MEANS[n], inv = 1.f / STDEV[n];
  for (int i = tid; i < 8192; i += 256) pw[i >> 9][i & 511] = wv[i];
  if (tid < 128) {
    int pp = tid >> 4, j = tid & 15;
    int l = (pb * 8 + pp) * 8 + j;
    if (l > 511) l = 511;                       // replication pad
    pat[pp][j] = (xe[((size_t)b * 512 + l) * 21 + c] - mean) * inv;
  }
  __syncthreads();
  for (int i = tid; i < 4096; i += 256) {
    int pp = i >> 9, d = i & 511;
    int p = pb * 8 + pp;
    float s = PE[p * 512 + d];
#pragma unroll
    for (int j = 0; j < 16; j++) s += pat[pp][j] * pw[j][d];
    X[((size_t)n * 64 + p) * 512 + d] = f2bf(s);
  }
}

// ---------------------------------------------------------------- topk / softw
__global__ __launch_bounds__(64) void topk_kernel(
    const float* __restrict__ MC, int* __restrict__ TIDX) {
  __shared__ float g[64];
  int tau = threadIdx.x;
  float s = 0.f;
  for (int n = 0; n < 672; n++) s += MC[n * 64 + tau];
  g[tau] = s;
  __syncthreads();
  if (tau == 0) {
    for (int j = 0; j < 4; j++) {
      int best = 0; float bv = -1e30f;
      for (int t = 0; t < 64; t++) if (g[t] > bv) { bv = g[t]; best = t; }
      TIDX[j] = best;
      g[best] = -1e30f;
    }
  }
}

__global__ __launch_bounds__(256) void softw_kernel(
    const float* __restrict__ MC, const int* __restrict__ TIDX, float* __restrict__ WSM) {
  int n = blockIdx.x * 256 + threadIdx.x;
  if (n >= 672) return;
  float v[4], mx = -1e30f;
#pragma unroll
  for (int j = 0; j < 4; j++) { v[j] = MC[n * 64 + TIDX[j]]; mx = fmaxf(mx, v[j]); }
  float s = 0.f;
#pragma unroll
  for (int j = 0; j < 4; j++) { v[j] = __expf(v[j] - mx); s += v[j]; }
  float inv = 1.f / s;
#pragma unroll
  for (int j = 0; j < 4; j++) WSM[n * 4 + j] = v[j] * inv;
}

// agg[n,l,d] = sum_j w[n,j] * v[n,(l+delay_j)&63,d]
__global__ __launch_bounds__(256) void agg_kernel(
    const u16* __restrict__ V, const float* __restrict__ WSM,
    const int* __restrict__ TIDX, u16* __restrict__ OUT) {
  int n = blockIdx.x;
  __shared__ float w[4];
  __shared__ int dly[4];
  int tid = threadIdx.x;
  if (tid < 4) { w[tid] = WSM[n * 4 + tid]; dly[tid] = TIDX[tid]; }
  __syncthreads();
  for (int i = tid; i < 64 * 512; i += 256) {
    int l = i >> 9, d = i & 511;
    float s = 0.f;
#pragma unroll
    for (int j = 0; j < 4; j++)
      s += w[j] * bf2f(V[((size_t)n * 64 + ((l + dly[j]) & 63)) * 512 + d]);
    OUT[((size_t)n * 64 + l) * 512 + d] = f2bf(s);
  }
}

// ---------------------------------------------------------------- full attention
// per (n,h): 64x64 q,k,v; scores=qk^T/8; softmax; out=Pv -> written over Q.
__global__ __launch_bounds__(256) void attn_kernel(
    u16* __restrict__ Q, const u16* __restrict__ Kb, const u16* __restrict__ Vb) {
  __shared__ u16 lq[64][72], lk[64][72], lv[64][72];
  __shared__ float lp[64][64];                          // [s][l]
  int n = blockIdx.x >> 3, h = blockIdx.x & 7;
  size_t base = ((size_t)n * 64) * 512 + (size_t)h * 64;
  int tid = threadIdx.x;
  int r = tid >> 2, c0 = (tid & 3) * 16;
  *(u16x8*)&lq[r][c0]     = *(const u16x8*)&Q[base + (size_t)r * 512 + c0];
  *(u16x8*)&lq[r][c0 + 8] = *(const u16x8*)&Q[base + (size_t)r * 512 + c0 + 8];
  *(u16x8*)&lk[r][c0]     = *(const u16x8*)&Kb[base + (size_t)r * 512 + c0];
  *(u16x8*)&lk[r][c0 + 8] = *(const u16x8*)&Kb[base + (size_t)r * 512 + c0 + 8];
  *(u16x8*)&lv[r][c0]     = *(const u16x8*)&Vb[base + (size_t)r * 512 + c0];
  *(u16x8*)&lv[r][c0 + 8] = *(const u16x8*)&Vb[base + (size_t)r * 512 + c0 + 8];
  __syncthreads();
  int lane = tid & 63, w = tid >> 6;
  int l = w * 16 + (lane & 15);
  int sq = lane >> 4;
  float sc[16];
#pragma unroll
  for (int j = 0; j < 16; j++) sc[j] = 0.f;
  for (int e0 = 0; e0 < 64; e0 += 8) {
    u16x8 q8 = *(const u16x8*)&lq[l][e0];
    float qv[8];
#pragma unroll
    for (int j = 0; j < 8; j++) qv[j] = bf2f(q8[j]);
#pragma unroll
    for (int s = 0; s < 16; s++) {
      u16x8 k8 = *(const u16x8*)&lk[sq * 16 + s][e0];
#pragma unroll
      for (int j = 0; j < 8; j++) sc[s] += qv[j] * bf2f(k8[j]);
    }
  }
  float mx = -1e30f;
#pragma unroll
  for (int j = 0; j < 16; j++) { sc[j] *= 0.125f; mx = fmaxf(mx, sc[j]); }
  mx = fmaxf(mx, __shfl_xor(mx, 16));
  mx = fmaxf(mx, __shfl_xor(mx, 32));
  float sum = 0.f;
#pragma unroll
  for (int j = 0; j < 16; j++) { sc[j] = __expf(sc[j] - mx); sum += sc[j]; }
  sum += __shfl_xor(sum, 16);
  sum += __shfl_xor(sum, 32);
  float inv = 1.f / sum;
#pragma unroll
  for (int j = 0; j < 16; j++) lp[sq * 16 + j][l] = sc[j] * inv;
  __syncthreads();
  float o[16];
#pragma unroll
  for (int j = 0; j < 16; j++) o[j] = 0.f;
  for (int s = 0; s < 64; s++) {
    float p = lp[s][l];
    u16x8 v0 = *(const u16x8*)&lv[s][sq * 16];
    u16x8 v1 = *(const u16x8*)&lv[s][sq * 16 + 8];
#pragma unroll
    for (int j = 0; j < 8; j++) { o[j] += p * bf2f(v0[j]); o[8 + j] += p * bf2f(v1[j]); }
  }
  u16x8 w0, w1;
#pragma unroll
  for (int j = 0; j < 8; j++) { w0[j] = f2bf(o[j]); w1[j] = f2bf(o[8 + j]); }
  *(u16x8*)&Q[base + (size_t)l * 512 + sq * 16] = w0;
  *(u16x8*)&Q[base + (size_t)l * 512 + sq * 16 + 8] = w1;
}

// ---------------------------------------------------------------- series decomp
// X <- (X + DELTA) - movavg_25_edge_replicated(X + DELTA), per (n,d) over l
__global__ __launch_bounds__(256) void decomp_kernel(
    u16* __restrict__ X, const u16* __restrict__ DELTA) {
  int n = blockIdx.x >> 1;
  int d = ((blockIdx.x & 1) << 8) + threadIdx.x;
  size_t base = ((size_t)n * 64) * 512 + d;
  float v[64];
#pragma unroll
  for (int l = 0; l < 64; l++)
    v[l] = bf2f(X[base + (size_t)l * 512]) + bf2f(DELTA[base + (size_t)l * 512]);
  float s = 12.f * v[0];
#pragma unroll
  for (int t = 0; t <= 12; t++) s += v[t];
#pragma unroll
  for (int l = 0; l < 64; l++) {
    float out = v[l] - s * (1.f / 25.f);
    X[base + (size_t)l * 512] = f2bf(out);
    if (l < 63) {
      int add = l + 13; if (add > 63) add = 63;
      int sub = l - 12; if (sub < 0) sub = 0;
      s += v[add] - v[sub];
    }
  }
}

// ---------------------------------------------------------------- batchnorm
__global__ __launch_bounds__(256) void bn_part(
    const u16* __restrict__ X, float* __restrict__ PS) {
  int ch = blockIdx.x, tid = threadIdx.x;
  float s1a = 0, s2a = 0, s1b = 0, s2b = 0;
  size_t base = (size_t)ch * 128 * 512;
  for (int r = 0; r < 128; r++) {
    float a = bf2f(X[base + (size_t)r * 512 + tid]);
    float b = bf2f(X[base + (size_t)r * 512 + tid + 256]);
    s1a += a; s2a += a * a; s1b += b; s2b += b * b;
  }
  PS[(size_t)(ch * 2 + 0) * 512 + tid] = s1a;
  PS[(size_t)(ch * 2 + 0) * 512 + tid + 256] = s1b;
  PS[(size_t)(ch * 2 + 1) * 512 + tid] = s2a;
  PS[(size_t)(ch * 2 + 1) * 512 + tid + 256] = s2b;
}

__global__ __launch_bounds__(256) void bn_final(
    const float* __restrict__ PS, const float* __restrict__ g,
    const float* __restrict__ b, float* __restrict__ SCALE, float* __restrict__ SHIFT) {
  int d = blockIdx.x * 256 + threadIdx.x;   // < 512
  float s = 0, ss = 0;
  for (int c = 0; c < 336; c++) {
    s += PS[(size_t)(c * 2) * 512 + d];
    ss += PS[(size_t)(c * 2 + 1) * 512 + d];
  }
  float mu = s * (1.f / 43008.f);
  float var = ss * (1.f / 43008.f) - mu * mu;
  float inv = 1.f / sqrtf(var + 1e-5f);
  float sc = g[d] * inv;
  SCALE[d] = sc;
  SHIFT[d] = b[d] - mu * sc;
}

// ---------------------------------------------------------------- bn transpose
// ENC[n][d*64+p] = bn(X[n][p][d]); LDS-tiled so both sides are coalesced.
__global__ __launch_bounds__(256) void bn_transpose_kernel(
    const u16* __restrict__ X, const float* __restrict__ SCALE,
    const float* __restrict__ SHIFT, u16* __restrict__ ENC) {
  __shared__ u16 t[64][72];
  int n = blockIdx.x >> 3, dc = (blockIdx.x & 7) * 64;
  int tid = threadIdx.x;
  for (int i = tid; i < 4096; i += 256) {
    int p = i >> 6, d = i & 63;
    float v = bf2f(X[((size_t)n * 64 + p) * 512 + dc + d]) * SCALE[dc + d] + SHIFT[dc + d];
    t[p][d] = f2bf(v);
  }
  __syncthreads();
  for (int i = tid; i < 4096; i += 256) {
    int d = i >> 6, p = i & 63;
    ENC[(size_t)n * 32768 + (size_t)(dc + d) * 64 + p] = t[p][d];
  }
}

// ---------------------------------------------------------------- head GEMM
// PART[kc][672][96] partial over 16 K-chunks; A = ENC (contiguous rows of 32768)
__global__ __launch_bounds__(256) void head_gemm(
    const u16* __restrict__ ENC, const u16* __restrict__ Wht,
    float* __restrict__ PART) {
  __shared__ u16 lA[64][40];
  __shared__ u16 lB[96][40];
  int bm = blockIdx.x;   // 0..10
  int kc = blockIdx.y;   // 0..15
  int tid = threadIdx.x, lane = tid & 63, w = tid >> 6;
  int sr = tid >> 2, sc0 = (tid & 3) * 8;
  f32x4 acc[6];
#pragma unroll
  for (int i = 0; i < 6; i++) acc[i] = (f32x4){0.f, 0.f, 0.f, 0.f};
  for (int kk0 = 0; kk0 < 2048; kk0 += 32) {
    int k0 = kc * 2048 + kk0;
    *(u16x8*)&lA[sr][sc0] =
        *(const u16x8*)&ENC[(size_t)(bm * 64 + sr) * 32768 + k0 + sc0];
    for (int i = tid; i < 96 * 4; i += 256) {
      int rB = i >> 2, seg = (i & 3) * 8;
      *(u16x8*)&lB[rB][seg] = *(const u16x8*)&Wht[(size_t)rB * 32768 + k0 + seg];
    }
    __syncthreads();
    int ar = w * 16 + (lane & 15);
    int kk = (lane >> 4) * 8;
    s16x8 af = *(const s16x8*)&lA[ar][kk];
#pragma unroll
    for (int nb = 0; nb < 6; nb++) {
      s16x8 bfr = *(const s16x8*)&lB[nb * 16 + (lane & 15)][kk];
      acc[nb] = __builtin_amdgcn_mfma_f32_16x16x32_bf16(af, bfr, acc[nb], 0, 0, 0);
    }
    __syncthreads();
  }
  int rb = bm * 64 + w * 16 + ((lane >> 4) << 2);
  int cl = lane & 15;
#pragma unroll
  for (int nb = 0; nb < 6; nb++) {
    int col = nb * 16 + cl;
#pragma unroll
    for (int r = 0; r < 4; r++) {
      int row = rb + r;
      if (row < 672) PART[((size_t)kc * 672 + row) * 96 + col] = acc[nb][r];
    }
  }
}

__global__ __launch_bounds__(256) void head_reduce(
    const float* __restrict__ PART, const float* __restrict__ bh,
    const float* __restrict__ STDEV, const float* __restrict__ MEANS,
    float* __restrict__ OUT) {
  int i = blockIdx.x * 256 + threadIdx.x;
  if (i >= 672 * 96) return;
  int n = i / 96, r = i % 96;
  float s = bh[r];
  for (int kc = 0; kc < 16; kc++) s += PART[((size_t)kc * 672 + n) * 96 + r];
  int b = n / 21, c = n % 21;
  OUT[((size_t)b * 96 + r) * 21 + c] = s * STDEV[n] + MEANS[n];
}

// ============================================================================
extern "C" void kernel_launch(void* const* d_in, const int* in_sizes, int n_in,
                              void* d_out, int out_size, void* d_ws, size_t ws_size,
                              hipStream_t stream) {
  const float* x_enc = (const float*)d_in[0];
  const float* w_val = (const float*)d_in[1];
  const float* Wq_ac = (const float*)d_in[2];
  const float* Wk_ac = (const float*)d_in[3];
  const float* Wv_ac = (const float*)d_in[4];
  const float* Wo_ac = (const float*)d_in[5];
  const float* bq_ac = (const float*)d_in[6];
  const float* bk_ac = (const float*)d_in[7];
  const float* bv_ac = (const float*)d_in[8];
  const float* bo_ac = (const float*)d_in[9];
  const float* Wq_sa = (const float*)d_in[10];
  const float* Wk_sa = (const float*)d_in[11];
  const float* Wv_sa = (const float*)d_in[12];
  const float* Wo_sa = (const float*)d_in[13];
  const float* bq_sa = (const float*)d_in[14];
  const float* bk_sa = (const float*)d_in[15];
  const float* bv_sa = (const float*)d_in[16];
  const float* bo_sa = (const float*)d_in[17];
  const float* WfW   = (const float*)d_in[18];
  const float* bfW   = (const float*)d_in[19];
  const float* W1    = (const float*)d_in[20];
  const float* W2    = (const float*)d_in[21];
  const float* bn_g  = (const float*)d_in[22];
  const float* bn_b  = (const float*)d_in[23];
  const float* W_head = (const float*)d_in[24];
  const float* b_head = (const float*)d_in[25];
  (void)in_sizes; (void)n_in; (void)out_size;

  // ---- workspace carve-up (~217 MB)
  char* wsp = (char*)d_ws;
  size_t off = 0;
  auto alloc = [&](size_t bytes) -> void* {
    void* p = wsp + off;
    off += (bytes + 255) & ~(size_t)255;
    return p;
  };
  u16* X    = (u16*)alloc((size_t)MROWS * 512 * 2);
  u16* P1   = (u16*)alloc((size_t)MROWS * 512 * 2);
  u16* P2   = (u16*)alloc((size_t)MROWS * 512 * 2);
  u16* P3   = (u16*)alloc((size_t)MROWS * 512 * 2);
  u16* WT   = (u16*)alloc((size_t)17301504 * 2);
  float* PE = (float*)alloc((size_t)32768 * 4);
  float* MEANS = (float*)alloc(672 * 4);
  float* STDEV = (float*)alloc(672 * 4);
  float* MC = (float*)alloc(672 * 64 * 4);
  int* TIDX = (int*)alloc(4 * 4);
  float* WSM = (float*)alloc(672 * 4 * 4);
  float* BNP = (float*)alloc((size_t)336 * 1024 * 4);
  float* SCALE = (float*)alloc(512 * 4);
  float* SHIFT = (float*)alloc(512 * 4);
  float* HEADP = (float*)alloc((size_t)16 * 672 * 96 * 4);
  // ENC (704 x 32768 bf16 = 46 MB) overlays P1+P2 (dead by head time)
  u16* ENC = P1;

  if (off > ws_size) {
    zero_out_kernel<<<252, 256, 0, stream>>>((float*)d_out, 672 * 96);
    return;
  }

  // ---- weight prep: transpose + bf16 convert
  u16* wtp = WT;
  auto tp = [&](const float* src, int K, int N) -> const u16* {
    u16* dst = wtp;
    transpose_cvt<<<dim3(K / 32, N / 32), dim3(32, 8), 0, stream>>>(src, dst, K, N);
    wtp += (size_t)K * N;
    return dst;
  };
  struct LW {
    const u16 *qac, *kac, *vac, *oac, *qsa, *ksa, *vsa, *osa, *wf, *w1, *w2;
  } lw[3];
  for (int l = 0; l < 3; l++) {
    lw[l].qac = tp(Wq_ac + (size_t)l * 262144, 512, 512);
    lw[l].kac = tp(Wk_ac + (size_t)l * 262144, 512, 512);
    lw[l].vac = tp(Wv_ac + (size_t)l * 262144, 512, 512);
    lw[l].oac = tp(Wo_ac + (size_t)l * 262144, 512, 512);
    lw[l].qsa = tp(Wq_sa + (size_t)l * 262144, 512, 512);
    lw[l].ksa = tp(Wk_sa + (size_t)l * 262144, 512, 512);
    lw[l].vsa = tp(Wv_sa + (size_t)l * 262144, 512, 512);
    lw[l].osa = tp(Wo_sa + (size_t)l * 262144, 512, 512);
    lw[l].wf  = tp(WfW   + (size_t)l * 524288, 1024, 512);
    lw[l].w1  = tp(W1    + (size_t)l * 1048576, 512, 2048);
    lw[l].w2  = tp(W2    + (size_t)l * 1048576, 2048, 512);
  }
  const u16* wht = tp(W_head, 32768, 96);

  // gemm: C[M,N] = A@Bt^T (+bias, relu); A row-stride lda
  auto gemm = [&](const u16* A, int lda, const u16* Bt, int ldb, const float* bias,
                  u16* C, int M, int N, int K, int relu) {
    gemm128<<<dim3(M / 128, N / 128), 256, 0, stream>>>(
        A, A, lda, K, Bt, ldb, bias, C, N, K, relu);
  };

  // ---- front end
  instnorm_kernel<<<672, 256, 0, stream>>>(x_enc, MEANS, STDEV);
  pe_kernel<<<128, 256, 0, stream>>>(PE);
  patch_kernel<<<672 * 8, 256, 0, stream>>>(x_enc, w_val, PE, MEANS, STDEV, X);

  // ---- encoder layers
  for (int l = 0; l < 3; l++) {
    const LW& w = lw[l];
    // Self-attention branch (leaves s in P2)
    gemm(X, 512, w.qsa, 512, bq_sa + l * 512, P1, MROWS, 512, 512, 0);
    gemm(X, 512, w.ksa, 512, bk_sa + l * 512, P2, MROWS, 512, 512, 0);
    gemm(X, 512, w.vsa, 512, bv_sa + l * 512, P3, MROWS, 512, 512, 0);
    attn_kernel<<<5376, 256, 0, stream>>>(P1, P2, P3);          // out -> P1
    gemm(P1, 512, w.osa, 512, bo_sa + l * 512, P2, MROWS, 512, 512, 0);  // s -> P2
    // AutoCorrelation branch (leaves a in P1)
    gemm(X, 512, w.qac, 512, bq_ac + l * 512, P1, MROWS, 512, 512, 0);
    gemm(X, 512, w.kac, 512, bk_ac + l * 512, P3, MROWS, 512, 512, 0);
    gram_mc_kernel<<<672, 256, 0, stream>>>(P1, P3, MC);
    topk_kernel<<<1, 64, 0, stream>>>(MC, TIDX);
    softw_kernel<<<3, 256, 0, stream>>>(MC, TIDX, WSM);
    gemm(X, 512, w.vac, 512, bv_ac + l * 512, P1, MROWS, 512, 512, 0);   // v
    agg_kernel<<<672, 256, 0, stream>>>(P1, WSM, TIDX, P3);
    gemm(P3, 512, w.oac, 512, bo_ac + l * 512, P1, MROWS, 512, 512, 0);  // a -> P1
    // fused = cat(a, s) @ Wf + bf  (dual-A via ksplit)
    gemm128<<<dim3(336, 4), 256, 0, stream>>>(
        P1, P2, 512, 512, w.wf, 1024, bfW + l * 512, P3, 512, 1024, 0);
    decomp_kernel<<<1344, 256, 0, stream>>>(X, P3);
    // FFN in 4 M-chunks (hidden reuses P3: 10752*2048*2 = 44 MB)
    for (int c = 0; c < 4; c++) {
      const u16* Xc = X + (size_t)c * 10752 * 512;
      u16* Yc = P1 + (size_t)c * 10752 * 512;
      gemm(Xc, 512, w.w1, 512, nullptr, P3, 10752, 2048, 512, 1);
      gemm(P3, 2048, w.w2, 2048, nullptr, Yc, 10752, 512, 2048, 0);
    }
    decomp_kernel<<<1344, 256, 0, stream>>>(X, P1);
  }

  // ---- batchnorm + head
  bn_part<<<336, 256, 0, stream>>>(X, BNP);
  bn_final<<<2, 256, 0, stream>>>(BNP, bn_g, bn_b, SCALE, SHIFT);
  bn_transpose_kernel<<<672 * 8, 256, 0, stream>>>(X, SCALE, SHIFT, ENC);
  head_gemm<<<dim3(11, 16), 256, 0, stream>>>(ENC, wht, HEADP);
  head_reduce<<<252, 256, 0, stream>>>(HEADP, b_head, STDEV, MEANS, (float*)d_out);
}

// Round 4
// 3055.284 us; speedup vs baseline: 1.4665x; 1.0908x over previous
//
#include <hip/hip_runtime.h>
#include <math.h>

// ============================================================================
// PatchTST/Autoformer hybrid forward on MI355X (gfx950).  Round 4.
//  - gemm128: m97-structure GEMM (128x128, BK=32, global_load_lds w16),
//    dual-A ksplit, ldc!=N, 3-section bias (for fused QKV).
//  - QKV region = one [43008][1536] buffer (3 column slices, stride 1536);
//    SA Q/K/V projections fused into one N=1536 GEMM.
//  - attn_mfma: per-(n,h) QK^T + softmax + PV entirely on the matrix pipe.
//  - AutoCorrelation: per-seq 64x64 Gram fused to mean_corr, top-4, gather.
// ============================================================================

typedef unsigned short u16;
typedef short s16x8 __attribute__((ext_vector_type(8)));
typedef u16 u16x8 __attribute__((ext_vector_type(8)));
typedef float f32x4 __attribute__((ext_vector_type(4)));

#define MROWS 43008   // 672 * 64
#define NSEQ  672
#define DM    512

__device__ __forceinline__ float bf2f(u16 b) {
  union { unsigned u; float f; } v; v.u = ((unsigned)b) << 16; return v.f;
}
__device__ __forceinline__ u16 f2bf(float f) {
  union { float f; unsigned u; } v; v.f = f;
  unsigned r = v.u + 0x7FFFu + ((v.u >> 16) & 1u);
  return (u16)(r >> 16);
}

// async global->LDS, 16 B per lane. LDS dest = wave-uniform base + lane*16.
__device__ __forceinline__ void gload16(const u16* g, u16* l) {
  __builtin_amdgcn_global_load_lds(
      (const __attribute__((address_space(1))) unsigned int*)g,
      (__attribute__((address_space(3))) unsigned int*)l, 16, 0, 0);
}

// ---------------------------------------------------------------- fallback
__global__ __launch_bounds__(256) void zero_out_kernel(float* __restrict__ o, int n) {
  int i = blockIdx.x * 256 + threadIdx.x;
  if (i < n) o[i] = 0.f;
}

// ---------------------------------------------------------------- transpose
// W [K,N] fp32 -> Wt [N,K] bf16
__global__ __launch_bounds__(256) void transpose_cvt(
    const float* __restrict__ W, u16* __restrict__ Wt, int K, int N) {
  __shared__ float t[32][33];
  int k0 = blockIdx.x * 32, n0 = blockIdx.y * 32;
  int tx = threadIdx.x, ty = threadIdx.y;   // 32 x 8
#pragma unroll
  for (int i = 0; i < 32; i += 8)
    t[ty + i][tx] = W[(size_t)(k0 + ty + i) * N + n0 + tx];
  __syncthreads();
#pragma unroll
  for (int i = 0; i < 32; i += 8)
    Wt[(size_t)(n0 + ty + i) * K + k0 + tx] = f2bf(t[tx][ty + i]);
}

// ---------------------------------------------------------------- gemm128
// C[M,N](bf16, row-stride ldc) = A[M,K] @ Bt[N,K]^T + bias, opt relu.
// A rows: A1 for k<ksplit else A2 (k-ksplit); both row-stride lda.
// bias section: col<512 -> b0, <1024 -> b1, else b2 (each indexed col&511).
__global__ __launch_bounds__(256) void gemm128(
    const u16* __restrict__ A1, const u16* __restrict__ A2, int lda, int ksplit,
    const u16* __restrict__ Bt, int ldb,
    const float* __restrict__ b0, const float* __restrict__ b1,
    const float* __restrict__ b2,
    u16* __restrict__ C, int ldc, int K, int relu) {
  __shared__ u16 lA[128 * 32];
  __shared__ u16 lB[128 * 32];
  int m0 = blockIdx.x * 128, n0 = blockIdx.y * 128;
  int tid = threadIdx.x, lane = tid & 63, w = tid >> 6;
  int wr = w >> 1, wc = w & 1;
  int srow = w * 16 + (lane >> 2);
  int scol = (lane & 3) * 8;
  f32x4 acc[4][4];
#pragma unroll
  for (int i = 0; i < 4; i++)
#pragma unroll
    for (int j = 0; j < 4; j++) acc[i][j] = (f32x4){0.f, 0.f, 0.f, 0.f};
  int m_in = lane & 15;
  int ks = (lane >> 4) * 8;
  for (int k0 = 0; k0 < K; k0 += 32) {
    const u16* Ab;
    int kk;
    if (k0 < ksplit) { Ab = A1; kk = k0; } else { Ab = A2; kk = k0 - ksplit; }
    gload16(&Ab[(size_t)(m0 + srow) * lda + kk + scol],        lA + w * 512);
    gload16(&Ab[(size_t)(m0 + 64 + srow) * lda + kk + scol],   lA + 2048 + w * 512);
    gload16(&Bt[(size_t)(n0 + srow) * ldb + k0 + scol],        lB + w * 512);
    gload16(&Bt[(size_t)(n0 + 64 + srow) * ldb + k0 + scol],   lB + 2048 + w * 512);
    __syncthreads();
    s16x8 a_[4], b_[4];
#pragma unroll
    for (int mf = 0; mf < 4; mf++)
      a_[mf] = *(const s16x8*)&lA[(wr * 64 + mf * 16 + m_in) * 32 + ks];
#pragma unroll
    for (int nf = 0; nf < 4; nf++)
      b_[nf] = *(const s16x8*)&lB[(wc * 64 + nf * 16 + m_in) * 32 + ks];
#pragma unroll
    for (int mf = 0; mf < 4; mf++)
#pragma unroll
      for (int nf = 0; nf < 4; nf++)
        acc[mf][nf] = __builtin_amdgcn_mfma_f32_16x16x32_bf16(
            a_[mf], b_[nf], acc[mf][nf], 0, 0, 0);
    __syncthreads();
  }
  // C/D layout: col = lane&15, row = (lane>>4)*4 + reg   [m89/m91]
  int r0 = m0 + wr * 64 + ((lane >> 4) << 2);
  int cl = lane & 15;
#pragma unroll
  for (int mf = 0; mf < 4; mf++) {
#pragma unroll
    for (int nf = 0; nf < 4; nf++) {
      int col = n0 + wc * 64 + nf * 16 + cl;
      const float* bp = (col < 512) ? b0 : (col < 1024 ? b1 : b2);
      float bv = bp ? bp[col & 511] : 0.f;
#pragma unroll
      for (int r = 0; r < 4; r++) {
        float v = acc[mf][nf][r] + bv;
        if (relu) v = fmaxf(v, 0.f);
        C[(size_t)(r0 + mf * 16 + r) * ldc + col] = f2bf(v);
      }
    }
  }
}

// ---------------------------------------------------------------- gram + mc
// Per seq n: G[t][s] = sum_d q[t,d]*k[s,d]; MC[n,tau] = sum_t G[t][(t-tau)&63]/512.
// q,k row-stride `ld`.
__global__ __launch_bounds__(256) void gram_mc_kernel(
    const u16* __restrict__ Q, const u16* __restrict__ K, int ld,
    float* __restrict__ MC) {
  __shared__ u16 lA[64][40];
  __shared__ u16 lB[64][40];
  __shared__ float red[64];
  int n = blockIdx.x;
  int tid = threadIdx.x, lane = tid & 63, w = tid >> 6;
  int sr = tid >> 2, scol = (tid & 3) * 8;
  if (tid < 64) red[tid] = 0.f;
  f32x4 acc[4];
#pragma unroll
  for (int i = 0; i < 4; i++) acc[i] = (f32x4){0.f, 0.f, 0.f, 0.f};
  size_t base = (size_t)n * 64 * ld;
  for (int k0 = 0; k0 < 512; k0 += 32) {
    *(u16x8*)&lA[sr][scol] = *(const u16x8*)&Q[base + (size_t)sr * ld + k0 + scol];
    *(u16x8*)&lB[sr][scol] = *(const u16x8*)&K[base + (size_t)sr * ld + k0 + scol];
    __syncthreads();
    int ar = w * 16 + (lane & 15);
    int kk = (lane >> 4) * 8;
    s16x8 af = *(const s16x8*)&lA[ar][kk];
#pragma unroll
    for (int nb = 0; nb < 4; nb++) {
      s16x8 bfr = *(const s16x8*)&lB[nb * 16 + (lane & 15)][kk];
      acc[nb] = __builtin_amdgcn_mfma_f32_16x16x32_bf16(af, bfr, acc[nb], 0, 0, 0);
    }
    __syncthreads();
  }
  int row0 = w * 16 + ((lane >> 4) << 2);
  int cl = lane & 15;
#pragma unroll
  for (int nb = 0; nb < 4; nb++) {
    int col = nb * 16 + cl;
#pragma unroll
    for (int r = 0; r < 4; r++)
      atomicAdd(&red[(row0 + r - col) & 63], acc[nb][r]);
  }
  __syncthreads();
  if (tid < 64) MC[n * 64 + tid] = red[tid] * (1.f / 512.f);
}

// ---------------------------------------------------------------- inst norm
__global__ __launch_bounds__(256) void instnorm_kernel(
    const float* __restrict__ xe, float* __restrict__ MEANS, float* __restrict__ STDEV) {
  int n = blockIdx.x;           // b*21+c
  int b = n / 21, c = n % 21;
  int tid = threadIdx.x;
  float v0 = xe[((size_t)b * 512 + tid) * 21 + c];
  float v1 = xe[((size_t)b * 512 + tid + 256) * 21 + c];
  float s = v0 + v1, ss = v0 * v0 + v1 * v1;
  for (int o = 32; o; o >>= 1) { s += __shfl_down(s, o); ss += __shfl_down(ss, o); }
  __shared__ float rs[4], rss[4];
  if ((tid & 63) == 0) { rs[tid >> 6] = s; rss[tid >> 6] = ss; }
  __syncthreads();
  if (tid == 0) {
    s = rs[0] + rs[1] + rs[2] + rs[3];
    ss = rss[0] + rss[1] + rss[2] + rss[3];
    float mean = s * (1.f / 512.f);
    float var = ss * (1.f / 512.f) - mean * mean;
    MEANS[n] = mean;
    STDEV[n] = sqrtf(var + 1e-5f);
  }
}

// ---------------------------------------------------------------- pos emb
__global__ __launch_bounds__(256) void pe_kernel(float* __restrict__ PE) {
  int i = blockIdx.x * 256 + threadIdx.x;  // 32768
  int p = i >> 9, d = i & 511;
  int k = d >> 1;
  float freq = expf(-(float)(2 * k) * (9.210340371976184f / 512.f));
  float ang = (float)p * freq;
  PE[i] = (d & 1) ? cosf(ang) : sinf(ang);
}

// ---------------------------------------------------------------- patch embed
__global__ __launch_bounds__(256) void patch_kernel(
    const float* __restrict__ xe, const float* __restrict__ wv,
    const float* __restrict__ PE, const float* __restrict__ MEANS,
    const float* __restrict__ STDEV, u16* __restrict__ X) {
  __shared__ float pw[16][512];
  __shared__ float pat[8][16];
  int bx = blockIdx.x;
  int n = bx >> 3, pb = bx & 7;
  int b = n / 21, c = n % 21;
  int tid = threadIdx.x;
  float mean = MEANS[n], inv = 1.f / STDEV[n];
  for (int i = tid; i < 8192; i += 256) pw[i >> 9][i & 511] = wv[i];
  if (tid < 128) {
    int pp = tid >> 4, j = tid & 15;
    int l = (pb * 8 + pp) * 8 + j;
    if (l > 511) l = 511;                       // replication pad
    pat[pp][j] = (xe[((size_t)b * 512 + l) * 21 + c] - mean) * inv;
  }
  __syncthreads();
  for (int i = tid; i < 4096; i += 256) {
    int pp = i >> 9, d = i & 511;
    int p = pb * 8 + pp;
    float s = PE[p * 512 + d];
#pragma unroll
    for (int j = 0; j < 16; j++) s += pat[pp][j] * pw[j][d];
    X[((size_t)n * 64 + p) * 512 + d] = f2bf(s);
  }
}

// ---------------------------------------------------------------- topk / softw
__global__ __launch_bounds__(64) void topk_kernel(
    const float* __restrict__ MC, int* __restrict__ TIDX) {
  __shared__ float g[64];
  int tau = threadIdx.x;
  float s = 0.f;
  for (int n = 0; n < 672; n++) s += MC[n * 64 + tau];
  g[tau] = s;
  __syncthreads();
  if (tau == 0) {
    for (int j = 0; j < 4; j++) {
      int best = 0; float bv = -1e30f;
      for (int t = 0; t < 64; t++) if (g[t] > bv) { bv = g[t]; best = t; }
      TIDX[j] = best;
      g[best] = -1e30f;
    }
  }
}

__global__ __launch_bounds__(256) void softw_kernel(
    const float* __restrict__ MC, const int* __restrict__ TIDX, float* __restrict__ WSM) {
  int n = blockIdx.x * 256 + threadIdx.x;
  if (n >= 672) return;
  float v[4], mx = -1e30f;
#pragma unroll
  for (int j = 0; j < 4; j++) { v[j] = MC[n * 64 + TIDX[j]]; mx = fmaxf(mx, v[j]); }
  float s = 0.f;
#pragma unroll
  for (int j = 0; j < 4; j++) { v[j] = __expf(v[j] - mx); s += v[j]; }
  float inv = 1.f / s;
#pragma unroll
  for (int j = 0; j < 4; j++) WSM[n * 4 + j] = v[j] * inv;
}

// agg[n,l,:] = sum_j w[n,j] * v[n,(l+delay_j)&63,:]   (V,OUT row-stride ld)
__global__ __launch_bounds__(256) void agg_kernel(
    const u16* __restrict__ V, int ld, const float* __restrict__ WSM,
    const int* __restrict__ TIDX, u16* __restrict__ OUT) {
  int n = blockIdx.x;
  __shared__ float w[4];
  __shared__ int dly[4];
  int tid = threadIdx.x;
  if (tid < 4) { w[tid] = WSM[n * 4 + tid]; dly[tid] = TIDX[tid]; }
  __syncthreads();
  for (int i = tid; i < 64 * 512; i += 256) {
    int l = i >> 9, d = i & 511;
    float s = 0.f;
#pragma unroll
    for (int j = 0; j < 4; j++)
      s += w[j] * bf2f(V[((size_t)n * 64 + ((l + dly[j]) & 63)) * ld + d]);
    OUT[((size_t)n * 64 + l) * ld + d] = f2bf(s);
  }
}

// ---------------------------------------------------------------- MFMA attention
// per (n,h): q,k,v 64x64 slices of QKV[43008][1536] (cols h*64 / 512+h*64 /
// 1024+h*64). scores = qk^T/8, softmax, out = P v -> overwrites q slice.
__global__ __launch_bounds__(256) void attn_mfma(u16* __restrict__ QKV) {
  __shared__ u16 lq[64][72], lk[64][72], lvt[64][72], lp[64][72];
  int n = blockIdx.x >> 3, h = blockIdx.x & 7;
  size_t base = (size_t)n * 64 * 1536;
  int qo = h * 64, ko = 512 + h * 64, vo = 1024 + h * 64;
  int tid = threadIdx.x, lane = tid & 63, w = tid >> 6;
  int r = tid >> 2, c0 = (tid & 3) * 16;
  *(u16x8*)&lq[r][c0]     = *(const u16x8*)&QKV[base + (size_t)r * 1536 + qo + c0];
  *(u16x8*)&lq[r][c0 + 8] = *(const u16x8*)&QKV[base + (size_t)r * 1536 + qo + c0 + 8];
  *(u16x8*)&lk[r][c0]     = *(const u16x8*)&QKV[base + (size_t)r * 1536 + ko + c0];
  *(u16x8*)&lk[r][c0 + 8] = *(const u16x8*)&QKV[base + (size_t)r * 1536 + ko + c0 + 8];
  u16x8 v0 = *(const u16x8*)&QKV[base + (size_t)r * 1536 + vo + c0];
  u16x8 v1 = *(const u16x8*)&QKV[base + (size_t)r * 1536 + vo + c0 + 8];
#pragma unroll
  for (int j = 0; j < 8; j++) { lvt[c0 + j][r] = v0[j]; lvt[c0 + 8 + j][r] = v1[j]; }
  __syncthreads();
  int m_in = lane & 15, ks = (lane >> 4) * 8;
  int rq = lane >> 4;   // row quad index
  s16x8 aq0 = *(const s16x8*)&lq[w * 16 + m_in][ks];
  s16x8 aq1 = *(const s16x8*)&lq[w * 16 + m_in][32 + ks];
  f32x4 s4[4];
#pragma unroll
  for (int nf = 0; nf < 4; nf++) {
    s4[nf] = (f32x4){0.f, 0.f, 0.f, 0.f};
    s16x8 b0 = *(const s16x8*)&lk[nf * 16 + m_in][ks];
    s16x8 b1 = *(const s16x8*)&lk[nf * 16 + m_in][32 + ks];
    s4[nf] = __builtin_amdgcn_mfma_f32_16x16x32_bf16(aq0, b0, s4[nf], 0, 0, 0);
    s4[nf] = __builtin_amdgcn_mfma_f32_16x16x32_bf16(aq1, b1, s4[nf], 0, 0, 0);
  }
  // row softmax: lane holds rows rq*4+r (r=0..3), cols nf*16 + m_in.
  float mx[4] = {-1e30f, -1e30f, -1e30f, -1e30f};
#pragma unroll
  for (int nf = 0; nf < 4; nf++)
#pragma unroll
    for (int r4 = 0; r4 < 4; r4++) {
      s4[nf][r4] *= 0.125f;
      mx[r4] = fmaxf(mx[r4], s4[nf][r4]);
    }
#pragma unroll
  for (int o = 1; o < 16; o <<= 1)
#pragma unroll
    for (int r4 = 0; r4 < 4; r4++) mx[r4] = fmaxf(mx[r4], __shfl_xor(mx[r4], o));
  float sum[4] = {0.f, 0.f, 0.f, 0.f};
#pragma unroll
  for (int nf = 0; nf < 4; nf++)
#pragma unroll
    for (int r4 = 0; r4 < 4; r4++) {
      float e = __expf(s4[nf][r4] - mx[r4]);
      s4[nf][r4] = e;
      sum[r4] += e;
    }
#pragma unroll
  for (int o = 1; o < 16; o <<= 1)
#pragma unroll
    for (int r4 = 0; r4 < 4; r4++) sum[r4] += __shfl_xor(sum[r4], o);
#pragma unroll
  for (int nf = 0; nf < 4; nf++)
#pragma unroll
    for (int r4 = 0; r4 < 4; r4++)
      lp[w * 16 + rq * 4 + r4][nf * 16 + m_in] = f2bf(s4[nf][r4] / sum[r4]);
  __syncthreads();
  // PV: out[m][d] = sum_s P[m][s] Vt[d][s]
  s16x8 ap0 = *(const s16x8*)&lp[w * 16 + m_in][ks];
  s16x8 ap1 = *(const s16x8*)&lp[w * 16 + m_in][32 + ks];
#pragma unroll
  for (int nf = 0; nf < 4; nf++) {
    f32x4 o4 = (f32x4){0.f, 0.f, 0.f, 0.f};
    s16x8 b0 = *(const s16x8*)&lvt[nf * 16 + m_in][ks];
    s16x8 b1 = *(const s16x8*)&lvt[nf * 16 + m_in][32 + ks];
    o4 = __builtin_amdgcn_mfma_f32_16x16x32_bf16(ap0, b0, o4, 0, 0, 0);
    o4 = __builtin_amdgcn_mfma_f32_16x16x32_bf16(ap1, b1, o4, 0, 0, 0);
#pragma unroll
    for (int r4 = 0; r4 < 4; r4++)
      QKV[base + (size_t)(w * 16 + rq * 4 + r4) * 1536 + qo + nf * 16 + m_in] =
          f2bf(o4[r4]);
  }
}

// ---------------------------------------------------------------- series decomp
// X <- (X + DELTA) - movavg_25_edge_replicated(X + DELTA); DELTA row-stride ds.
__global__ __launch_bounds__(256) void decomp_kernel(
    u16* __restrict__ X, const u16* __restrict__ DELTA, int ds) {
  int n = blockIdx.x >> 1;
  int d = ((blockIdx.x & 1) << 8) + threadIdx.x;
  size_t xb = ((size_t)n * 64) * 512 + d;
  size_t db = ((size_t)n * 64) * ds + d;
  float v[64];
#pragma unroll
  for (int l = 0; l < 64; l++)
    v[l] = bf2f(X[xb + (size_t)l * 512]) + bf2f(DELTA[db + (size_t)l * ds]);
  float s = 12.f * v[0];
#pragma unroll
  for (int t = 0; t <= 12; t++) s += v[t];
#pragma unroll
  for (int l = 0; l < 64; l++) {
    float out = v[l] - s * (1.f / 25.f);
    X[xb + (size_t)l * 512] = f2bf(out);
    if (l < 63) {
      int add = l + 13; if (add > 63) add = 63;
      int sub = l - 12; if (sub < 0) sub = 0;
      s += v[add] - v[sub];
    }
  }
}

// ---------------------------------------------------------------- batchnorm
__global__ __launch_bounds__(256) void bn_part(
    const u16* __restrict__ X, float* __restrict__ PS) {
  int ch = blockIdx.x, tid = threadIdx.x;
  float s1a = 0, s2a = 0, s1b = 0, s2b = 0;
  size_t base = (size_t)ch * 128 * 512;
  for (int r = 0; r < 128; r++) {
    float a = bf2f(X[base + (size_t)r * 512 + tid]);
    float b = bf2f(X[base + (size_t)r * 512 + tid + 256]);
    s1a += a; s2a += a * a; s1b += b; s2b += b * b;
  }
  PS[(size_t)(ch * 2 + 0) * 512 + tid] = s1a;
  PS[(size_t)(ch * 2 + 0) * 512 + tid + 256] = s1b;
  PS[(size_t)(ch * 2 + 1) * 512 + tid] = s2a;
  PS[(size_t)(ch * 2 + 1) * 512 + tid + 256] = s2b;
}

__global__ __launch_bounds__(256) void bn_final(
    const float* __restrict__ PS, const float* __restrict__ g,
    const float* __restrict__ b, float* __restrict__ SCALE, float* __restrict__ SHIFT) {
  int d = blockIdx.x * 256 + threadIdx.x;   // < 512
  float s = 0, ss = 0;
  for (int c = 0; c < 336; c++) {
    s += PS[(size_t)(c * 2) * 512 + d];
    ss += PS[(size_t)(c * 2 + 1) * 512 + d];
  }
  float mu = s * (1.f / 43008.f);
  float var = ss * (1.f / 43008.f) - mu * mu;
  float inv = 1.f / sqrtf(var + 1e-5f);
  float sc = g[d] * inv;
  SCALE[d] = sc;
  SHIFT[d] = b[d] - mu * sc;
}

// ---------------------------------------------------------------- bn transpose
// ENC[n][d*64+p] = bn(X[n][p][d]); LDS-tiled so both sides are coalesced.
__global__ __launch_bounds__(256) void bn_transpose_kernel(
    const u16* __restrict__ X, const float* __restrict__ SCALE,
    const float* __restrict__ SHIFT, u16* __restrict__ ENC) {
  __shared__ u16 t[64][72];
  int n = blockIdx.x >> 3, dc = (blockIdx.x & 7) * 64;
  int tid = threadIdx.x;
  for (int i = tid; i < 4096; i += 256) {
    int p = i >> 6, d = i & 63;
    float v = bf2f(X[((size_t)n * 64 + p) * 512 + dc + d]) * SCALE[dc + d] + SHIFT[dc + d];
    t[p][d] = f2bf(v);
  }
  __syncthreads();
  for (int i = tid; i < 4096; i += 256) {
    int d = i >> 6, p = i & 63;
    ENC[(size_t)n * 32768 + (size_t)(dc + d) * 64 + p] = t[p][d];
  }
}

// ---------------------------------------------------------------- head GEMM
// PART[kc][672][96] partial over 16 K-chunks; A = ENC (contiguous rows of 32768)
__global__ __launch_bounds__(256) void head_gemm(
    const u16* __restrict__ ENC, const u16* __restrict__ Wht,
    float* __restrict__ PART) {
  __shared__ u16 lA[64][40];
  __shared__ u16 lB[96][40];
  int bm = blockIdx.x;   // 0..10
  int kc = blockIdx.y;   // 0..15
  int tid = threadIdx.x, lane = tid & 63, w = tid >> 6;
  int sr = tid >> 2, sc0 = (tid & 3) * 8;
  f32x4 acc[6];
#pragma unroll
  for (int i = 0; i < 6; i++) acc[i] = (f32x4){0.f, 0.f, 0.f, 0.f};
  for (int kk0 = 0; kk0 < 2048; kk0 += 32) {
    int k0 = kc * 2048 + kk0;
    *(u16x8*)&lA[sr][sc0] =
        *(const u16x8*)&ENC[(size_t)(bm * 64 + sr) * 32768 + k0 + sc0];
    for (int i = tid; i < 96 * 4; i += 256) {
      int rB = i >> 2, seg = (i & 3) * 8;
      *(u16x8*)&lB[rB][seg] = *(const u16x8*)&Wht[(size_t)rB * 32768 + k0 + seg];
    }
    __syncthreads();
    int ar = w * 16 + (lane & 15);
    int kk = (lane >> 4) * 8;
    s16x8 af = *(const s16x8*)&lA[ar][kk];
#pragma unroll
    for (int nb = 0; nb < 6; nb++) {
      s16x8 bfr = *(const s16x8*)&lB[nb * 16 + (lane & 15)][kk];
      acc[nb] = __builtin_amdgcn_mfma_f32_16x16x32_bf16(af, bfr, acc[nb], 0, 0, 0);
    }
    __syncthreads();
  }
  int rb = bm * 64 + w * 16 + ((lane >> 4) << 2);
  int cl = lane & 15;
#pragma unroll
  for (int nb = 0; nb < 6; nb++) {
    int col = nb * 16 + cl;
#pragma unroll
    for (int r = 0; r < 4; r++) {
      int row = rb + r;
      if (row < 672) PART[((size_t)kc * 672 + row) * 96 + col] = acc[nb][r];
    }
  }
}

__global__ __launch_bounds__(256) void head_reduce(
    const float* __restrict__ PART, const float* __restrict__ bh,
    const float* __restrict__ STDEV, const float* __restrict__ MEANS,
    float* __restrict__ OUT) {
  int i = blockIdx.x * 256 + threadIdx.x;
  if (i >= 672 * 96) return;
  int n = i / 96, r = i % 96;
  float s = bh[r];
  for (int kc = 0; kc < 16; kc++) s += PART[((size_t)kc * 672 + n) * 96 + r];
  int b = n / 21, c = n % 21;
  OUT[((size_t)b * 96 + r) * 21 + c] = s * STDEV[n] + MEANS[n];
}

// ============================================================================
extern "C" void kernel_launch(void* const* d_in, const int* in_sizes, int n_in,
                              void* d_out, int out_size, void* d_ws, size_t ws_size,
                              hipStream_t stream) {
  const float* x_enc = (const float*)d_in[0];
  const float* w_val = (const float*)d_in[1];
  const float* Wq_ac = (const float*)d_in[2];
  const float* Wk_ac = (const float*)d_in[3];
  const float* Wv_ac = (const float*)d_in[4];
  const float* Wo_ac = (const float*)d_in[5];
  const float* bq_ac = (const float*)d_in[6];
  const float* bk_ac = (const float*)d_in[7];
  const float* bv_ac = (const float*)d_in[8];
  const float* bo_ac = (const float*)d_in[9];
  const float* Wq_sa = (const float*)d_in[10];
  const float* Wk_sa = (const float*)d_in[11];
  const float* Wv_sa = (const float*)d_in[12];
  const float* Wo_sa = (const float*)d_in[13];
  const float* bq_sa = (const float*)d_in[14];
  const float* bk_sa = (const float*)d_in[15];
  const float* bv_sa = (const float*)d_in[16];
  const float* bo_sa = (const float*)d_in[17];
  const float* WfW   = (const float*)d_in[18];
  const float* bfW   = (const float*)d_in[19];
  const float* W1    = (const float*)d_in[20];
  const float* W2    = (const float*)d_in[21];
  const float* bn_g  = (const float*)d_in[22];
  const float* bn_b  = (const float*)d_in[23];
  const float* W_head = (const float*)d_in[24];
  const float* b_head = (const float*)d_in[25];
  (void)in_sizes; (void)n_in; (void)out_size;

  // ---- workspace carve-up (~213 MB)
  char* wsp = (char*)d_ws;
  size_t off = 0;
  auto alloc = [&](size_t bytes) -> void* {
    void* p = wsp + off;
    off += (bytes + 255) & ~(size_t)255;
    return p;
  };
  u16* X    = (u16*)alloc((size_t)MROWS * 512 * 2);
  u16* Q3   = (u16*)alloc((size_t)MROWS * 1536 * 2);   // 3 column slices
  u16* WT   = (u16*)alloc((size_t)17301504 * 2);
  float* PE = (float*)alloc((size_t)32768 * 4);
  float* MEANS = (float*)alloc(672 * 4);
  float* STDEV = (float*)alloc(672 * 4);
  float* MC = (float*)alloc(672 * 64 * 4);
  int* TIDX = (int*)alloc(4 * 4);
  float* WSM = (float*)alloc(672 * 4 * 4);
  float* BNP = (float*)alloc((size_t)336 * 1024 * 4);
  float* SCALE = (float*)alloc(512 * 4);
  float* SHIFT = (float*)alloc(512 * 4);
  float* HEADP = (float*)alloc((size_t)16 * 672 * 96 * 4);
  // column-slice aliases (element offsets into rows of 1536)
  u16* C0 = Q3;          // cols    0..511
  u16* C1 = Q3 + 512;    // cols  512..1023
  u16* C2 = Q3 + 1024;   // cols 1024..1535
  // FFN scratch overlays Q3 (dead between decomp1 and decomp2):
  u16* HBUF = Q3;                                  // [10752][2048] = 44 MB
  u16* YBUF = Q3 + (size_t)2 * MROWS * 512;        // [43008][512]  = 44 MB
  u16* ENC  = Q3;                                  // head: [672][32768] = 44 MB

  if (off > ws_size) {
    zero_out_kernel<<<252, 256, 0, stream>>>((float*)d_out, 672 * 96);
    return;
  }

  // ---- weight prep: transpose + bf16 convert (qsa,ksa,vsa contiguous!)
  u16* wtp = WT;
  auto tp = [&](const float* src, int K, int N) -> const u16* {
    u16* dst = wtp;
    transpose_cvt<<<dim3(K / 32, N / 32), dim3(32, 8), 0, stream>>>(src, dst, K, N);
    wtp += (size_t)K * N;
    return dst;
  };
  struct LW {
    const u16 *qsa, *ksa, *vsa, *osa, *qac, *kac, *vac, *oac, *wf, *w1, *w2;
  } lw[3];
  for (int l = 0; l < 3; l++) {
    lw[l].qsa = tp(Wq_sa + (size_t)l * 262144, 512, 512);
    lw[l].ksa = tp(Wk_sa + (size_t)l * 262144, 512, 512);
    lw[l].vsa = tp(Wv_sa + (size_t)l * 262144, 512, 512);
    lw[l].osa = tp(Wo_sa + (size_t)l * 262144, 512, 512);
    lw[l].qac = tp(Wq_ac + (size_t)l * 262144, 512, 512);
    lw[l].kac = tp(Wk_ac + (size_t)l * 262144, 512, 512);
    lw[l].vac = tp(Wv_ac + (size_t)l * 262144, 512, 512);
    lw[l].oac = tp(Wo_ac + (size_t)l * 262144, 512, 512);
    lw[l].wf  = tp(WfW   + (size_t)l * 524288, 1024, 512);
    lw[l].w1  = tp(W1    + (size_t)l * 1048576, 512, 2048);
    lw[l].w2  = tp(W2    + (size_t)l * 1048576, 2048, 512);
  }
  const u16* wht = tp(W_head, 32768, 96);

  // plain gemm: C[M,N] = A@Bt^T + b0
  auto gemm = [&](const u16* A, int lda, const u16* Bt, int ldb, const float* b0,
                  u16* C, int ldc, int M, int N, int K, int relu) {
    gemm128<<<dim3(M / 128, N / 128), 256, 0, stream>>>(
        A, A, lda, K, Bt, ldb, b0, nullptr, nullptr, C, ldc, K, relu);
  };

  // ---- front end
  instnorm_kernel<<<672, 256, 0, stream>>>(x_enc, MEANS, STDEV);
  pe_kernel<<<128, 256, 0, stream>>>(PE);
  patch_kernel<<<672 * 8, 256, 0, stream>>>(x_enc, w_val, PE, MEANS, STDEV, X);

  // ---- encoder layers
  for (int l = 0; l < 3; l++) {
    const LW& w = lw[l];
    // SA: fused QKV (N=1536) -> Q3 cols [q|k|v]
    gemm128<<<dim3(336, 12), 256, 0, stream>>>(
        X, X, 512, 512, w.qsa, 512,
        bq_sa + l * 512, bk_sa + l * 512, bv_sa + l * 512, Q3, 1536, 512, 0);
    attn_mfma<<<5376, 256, 0, stream>>>(Q3);                      // out -> C0
    gemm(C0, 1536, w.osa, 512, bo_sa + l * 512, C1, 1536, MROWS, 512, 512, 0); // s->C1
    // AC branch
    gemm(X, 512, w.qac, 512, bq_ac + l * 512, C2, 1536, MROWS, 512, 512, 0);   // q->C2
    gemm(X, 512, w.kac, 512, bk_ac + l * 512, C0, 1536, MROWS, 512, 512, 0);   // k->C0
    gram_mc_kernel<<<672, 256, 0, stream>>>(C2, C0, 1536, MC);
    topk_kernel<<<1, 64, 0, stream>>>(MC, TIDX);
    softw_kernel<<<3, 256, 0, stream>>>(MC, TIDX, WSM);
    gemm(X, 512, w.vac, 512, bv_ac + l * 512, C2, 1536, MROWS, 512, 512, 0);   // v->C2
    agg_kernel<<<672, 256, 0, stream>>>(C2, 1536, WSM, TIDX, C0);              // ->C0
    gemm(C0, 1536, w.oac, 512, bo_ac + l * 512, C2, 1536, MROWS, 512, 512, 0); // a->C2
    // fused = cat(a, s) @ Wf + bf  (dual-A via ksplit) -> C0
    gemm128<<<dim3(336, 4), 256, 0, stream>>>(
        C2, C1, 1536, 512, w.wf, 1024,
        bfW + l * 512, nullptr, nullptr, C0, 1536, 1024, 0);
    decomp_kernel<<<1344, 256, 0, stream>>>(X, C0, 1536);
    // FFN in 4 M-chunks (hidden HBUF=Q3 base, y -> YBUF)
    for (int c = 0; c < 4; c++) {
      const u16* Xc = X + (size_t)c * 10752 * 512;
      u16* Yc = YBUF + (size_t)c * 10752 * 512;
      gemm(Xc, 512, w.w1, 512, nullptr, HBUF, 2048, 10752, 2048, 512, 1);
      gemm(HBUF, 2048, w.w2, 2048, nullptr, Yc, 512, 10752, 512, 2048, 0);
    }
    decomp_kernel<<<1344, 256, 0, stream>>>(X, YBUF, 512);
  }

  // ---- batchnorm + head
  bn_part<<<336, 256, 0, stream>>>(X, BNP);
  bn_final<<<2, 256, 0, stream>>>(BNP, bn_g, bn_b, SCALE, SHIFT);
  bn_transpose_kernel<<<672 * 8, 256, 0, stream>>>(X, SCALE, SHIFT, ENC);
  head_gemm<<<dim3(11, 16), 256, 0, stream>>>(ENC, wht, HEADP);
  head_reduce<<<252, 256, 0, stream>>>(HEADP, b_head, STDEV, MEANS, (float*)d_out);
}

// Round 5
// 2985.335 us; speedup vs baseline: 1.5008x; 1.0234x over previous
//
#include <hip/hip_runtime.h>
#include <math.h>

// ============================================================================
// PatchTST/Autoformer hybrid forward on MI355X (gfx950).  Round 5.
//  - gemm128p: 128x128 tile, BK=32, 3-deep global_load_lds pipeline with
//    counted vmcnt(8) (T3+T4), raw s_barrier, setprio around MFMA (T5),
//    both-sides LDS XOR swizzle (T2: pre-swizzled source + swizzled read),
//    n-inner 1D grid remap for A-panel L2/L3 reuse.
//  - QKV region [43008][1536]; SA q/k/v in one N=1536 GEMM; attn on MFMA.
//  - AutoCorrelation: per-seq 64x64 Gram fused to mean_corr, top-4, gather.
// ============================================================================

typedef unsigned short u16;
typedef short s16x8 __attribute__((ext_vector_type(8)));
typedef u16 u16x8 __attribute__((ext_vector_type(8)));
typedef float f32x4 __attribute__((ext_vector_type(4)));

#define MROWS 43008   // 672 * 64
#define NSEQ  672
#define DM    512

__device__ __forceinline__ float bf2f(u16 b) {
  union { unsigned u; float f; } v; v.u = ((unsigned)b) << 16; return v.f;
}
__device__ __forceinline__ u16 f2bf(float f) {
  union { float f; unsigned u; } v; v.f = f;
  unsigned r = v.u + 0x7FFFu + ((v.u >> 16) & 1u);
  return (u16)(r >> 16);
}

// async global->LDS, 16 B per lane. LDS dest = wave-uniform base + lane*16.
__device__ __forceinline__ void gload16(const u16* g, u16* l) {
  __builtin_amdgcn_global_load_lds(
      (const __attribute__((address_space(1))) unsigned int*)g,
      (__attribute__((address_space(3))) unsigned int*)l, 16, 0, 0);
}

// ---------------------------------------------------------------- fallback
__global__ __launch_bounds__(256) void zero_out_kernel(float* __restrict__ o, int n) {
  int i = blockIdx.x * 256 + threadIdx.x;
  if (i < n) o[i] = 0.f;
}

// ---------------------------------------------------------------- transpose
// W [K,N] fp32 -> Wt [N,K] bf16
__global__ __launch_bounds__(256) void transpose_cvt(
    const float* __restrict__ W, u16* __restrict__ Wt, int K, int N) {
  __shared__ float t[32][33];
  int k0 = blockIdx.x * 32, n0 = blockIdx.y * 32;
  int tx = threadIdx.x, ty = threadIdx.y;   // 32 x 8
#pragma unroll
  for (int i = 0; i < 32; i += 8)
    t[ty + i][tx] = W[(size_t)(k0 + ty + i) * N + n0 + tx];
  __syncthreads();
#pragma unroll
  for (int i = 0; i < 32; i += 8)
    Wt[(size_t)(n0 + ty + i) * K + k0 + tx] = f2bf(t[tx][ty + i]);
}

// ---------------------------------------------------------------- gemm128p
// C[M,N](bf16, row-stride ldc) = A[M,K] @ Bt[N,K]^T + bias, opt relu.
// A rows: A1 for k<ksplit else A2 (k-ksplit); both row-stride lda.
// bias sections: col<512 -> b0, <1024 -> b1, else b2 (indexed col&511).
// 1D grid: block g -> (bm = g/nb, bn = g%nb)  [n-inner: A-panel reuse].
// Pipeline: 3 LDS buffers, prefetch depth 2, vmcnt(8), raw barriers.
// LDS swizzle: slot' = slot ^ ((row>>1)&3)  (16B slots within 64B rows),
// applied on the global SOURCE column for staging and on the read offset.
__global__ __launch_bounds__(256) void gemm128p(
    const u16* __restrict__ A1, const u16* __restrict__ A2, int lda, int ksplit,
    const u16* __restrict__ Bt, int ldb,
    const float* __restrict__ b0, const float* __restrict__ b1,
    const float* __restrict__ b2,
    u16* __restrict__ C, int ldc, int K, int relu, int nb) {
  __shared__ u16 sm[3][8192];   // per buffer: A[128][32] @0, B[128][32] @4096
  int g = blockIdx.x;
  int m0 = (g / nb) * 128, n0 = (g % nb) * 128;
  int tid = threadIdx.x, lane = tid & 63, w = tid >> 6;
  int wr = w >> 1, wc = w & 1;
  // staging: rows w*16 + lane/4 (and +64), source col slot pre-swizzled
  int srow = w * 16 + (lane >> 2);
  int scol = (((lane & 3) ^ ((lane >> 3) & 3)) * 8);
  int m_in = lane & 15;
  int sgrp = lane >> 4;             // 0..3 (16B slot of the fragment)
  // loop-invariant swizzled read offsets (elements within a buffer)
  int offA[4], offB[4];
#pragma unroll
  for (int mf = 0; mf < 4; mf++) {
    int row = wr * 64 + mf * 16 + m_in;
    offA[mf] = row * 32 + ((sgrp ^ ((row >> 1) & 3)) * 8);
  }
#pragma unroll
  for (int nf = 0; nf < 4; nf++) {
    int row = wc * 64 + nf * 16 + m_in;
    offB[nf] = 4096 + row * 32 + ((sgrp ^ ((row >> 1) & 3)) * 8);
  }
  f32x4 acc[4][4];
#pragma unroll
  for (int i = 0; i < 4; i++)
#pragma unroll
    for (int j = 0; j < 4; j++) acc[i][j] = (f32x4){0.f, 0.f, 0.f, 0.f};

  int nt = K >> 5;
  auto STAGE = [&](int b, int t) {
    int k0 = t * 32;
    const u16* Ab; int kk;
    if (k0 < ksplit) { Ab = A1; kk = k0; } else { Ab = A2; kk = k0 - ksplit; }
    u16* base = &sm[b][0];
    gload16(&Ab[(size_t)(m0 + srow) * lda + kk + scol],      base + w * 512);
    gload16(&Ab[(size_t)(m0 + 64 + srow) * lda + kk + scol], base + 2048 + w * 512);
    gload16(&Bt[(size_t)(n0 + srow) * ldb + k0 + scol],      base + 4096 + w * 512);
    gload16(&Bt[(size_t)(n0 + 64 + srow) * ldb + k0 + scol], base + 6144 + w * 512);
  };

  STAGE(0, 0);
  STAGE(1, 1 < nt ? 1 : nt - 1);
  int cb = 0;
  for (int t = 0; t < nt; ++t) {
    int pf = t + 2 < nt ? t + 2 : nt - 1;
    int pb = cb + 2 >= 3 ? cb - 1 : cb + 2;
    STAGE(pb, pf);
    asm volatile("s_waitcnt vmcnt(8)" ::: "memory");
    asm volatile("s_barrier" ::: "memory");
    const u16* lb = &sm[cb][0];
    s16x8 a_[4], b_[4];
#pragma unroll
    for (int mf = 0; mf < 4; mf++) a_[mf] = *(const s16x8*)&lb[offA[mf]];
#pragma unroll
    for (int nf = 0; nf < 4; nf++) b_[nf] = *(const s16x8*)&lb[offB[nf]];
    __builtin_amdgcn_s_setprio(1);
#pragma unroll
    for (int mf = 0; mf < 4; mf++)
#pragma unroll
      for (int nf = 0; nf < 4; nf++)
        acc[mf][nf] = __builtin_amdgcn_mfma_f32_16x16x32_bf16(
            a_[mf], b_[nf], acc[mf][nf], 0, 0, 0);
    __builtin_amdgcn_s_setprio(0);
    asm volatile("s_barrier" ::: "memory");
    cb = cb + 1 >= 3 ? 0 : cb + 1;
  }
  // C/D layout: col = lane&15, row = (lane>>4)*4 + reg   [m89/m91]
  int r0 = m0 + wr * 64 + (sgrp << 2);
  int cl = lane & 15;
#pragma unroll
  for (int mf = 0; mf < 4; mf++) {
#pragma unroll
    for (int nf = 0; nf < 4; nf++) {
      int col = n0 + wc * 64 + nf * 16 + cl;
      const float* bp = (col < 512) ? b0 : (col < 1024 ? b1 : b2);
      float bv = bp ? bp[col & 511] : 0.f;
#pragma unroll
      for (int r = 0; r < 4; r++) {
        float v = acc[mf][nf][r] + bv;
        if (relu) v = fmaxf(v, 0.f);
        C[(size_t)(r0 + mf * 16 + r) * ldc + col] = f2bf(v);
      }
    }
  }
}

// ---------------------------------------------------------------- gram + mc
// Per seq n: G[t][s] = sum_d q[t,d]*k[s,d]; MC[n,tau] = sum_t G[t][(t-tau)&63]/512.
__global__ __launch_bounds__(256) void gram_mc_kernel(
    const u16* __restrict__ Q, const u16* __restrict__ K, int ld,
    float* __restrict__ MC) {
  __shared__ u16 lA[64][40];
  __shared__ u16 lB[64][40];
  __shared__ float red[64];
  int n = blockIdx.x;
  int tid = threadIdx.x, lane = tid & 63, w = tid >> 6;
  int sr = tid >> 2, scol = (tid & 3) * 8;
  if (tid < 64) red[tid] = 0.f;
  f32x4 acc[4];
#pragma unroll
  for (int i = 0; i < 4; i++) acc[i] = (f32x4){0.f, 0.f, 0.f, 0.f};
  size_t base = (size_t)n * 64 * ld;
  for (int k0 = 0; k0 < 512; k0 += 32) {
    *(u16x8*)&lA[sr][scol] = *(const u16x8*)&Q[base + (size_t)sr * ld + k0 + scol];
    *(u16x8*)&lB[sr][scol] = *(const u16x8*)&K[base + (size_t)sr * ld + k0 + scol];
    __syncthreads();
    int ar = w * 16 + (lane & 15);
    int kk = (lane >> 4) * 8;
    s16x8 af = *(const s16x8*)&lA[ar][kk];
#pragma unroll
    for (int nb = 0; nb < 4; nb++) {
      s16x8 bfr = *(const s16x8*)&lB[nb * 16 + (lane & 15)][kk];
      acc[nb] = __builtin_amdgcn_mfma_f32_16x16x32_bf16(af, bfr, acc[nb], 0, 0, 0);
    }
    __syncthreads();
  }
  int row0 = w * 16 + ((lane >> 4) << 2);
  int cl = lane & 15;
#pragma unroll
  for (int nb = 0; nb < 4; nb++) {
    int col = nb * 16 + cl;
#pragma unroll
    for (int r = 0; r < 4; r++)
      atomicAdd(&red[(row0 + r - col) & 63], acc[nb][r]);
  }
  __syncthreads();
  if (tid < 64) MC[n * 64 + tid] = red[tid] * (1.f / 512.f);
}

// ---------------------------------------------------------------- inst norm
__global__ __launch_bounds__(256) void instnorm_kernel(
    const float* __restrict__ xe, float* __restrict__ MEANS, float* __restrict__ STDEV) {
  int n = blockIdx.x;           // b*21+c
  int b = n / 21, c = n % 21;
  int tid = threadIdx.x;
  float v0 = xe[((size_t)b * 512 + tid) * 21 + c];
  float v1 = xe[((size_t)b * 512 + tid + 256) * 21 + c];
  float s = v0 + v1, ss = v0 * v0 + v1 * v1;
  for (int o = 32; o; o >>= 1) { s += __shfl_down(s, o); ss += __shfl_down(ss, o); }
  __shared__ float rs[4], rss[4];
  if ((tid & 63) == 0) { rs[tid >> 6] = s; rss[tid >> 6] = ss; }
  __syncthreads();
  if (tid == 0) {
    s = rs[0] + rs[1] + rs[2] + rs[3];
    ss = rss[0] + rss[1] + rss[2] + rss[3];
    float mean = s * (1.f / 512.f);
    float var = ss * (1.f / 512.f) - mean * mean;
    MEANS[n] = mean;
    STDEV[n] = sqrtf(var + 1e-5f);
  }
}

// ---------------------------------------------------------------- pos emb
__global__ __launch_bounds__(256) void pe_kernel(float* __restrict__ PE) {
  int i = blockIdx.x * 256 + threadIdx.x;  // 32768
  int p = i >> 9, d = i & 511;
  int k = d >> 1;
  float freq = expf(-(float)(2 * k) * (9.210340371976184f / 512.f));
  float ang = (float)p * freq;
  PE[i] = (d & 1) ? cosf(ang) : sinf(ang);
}

// ---------------------------------------------------------------- patch embed
__global__ __launch_bounds__(256) void patch_kernel(
    const float* __restrict__ xe, const float* __restrict__ wv,
    const float* __restrict__ PE, const float* __restrict__ MEANS,
    const float* __restrict__ STDEV, u16* __restrict__ X) {
  __shared__ float pw[16][512];
  __shared__ float pat[8][16];
  int bx = blockIdx.x;
  int n = bx >> 3, pb = bx & 7;
  int b = n / 21, c = n % 21;
  int tid = threadIdx.x;
  float mean = MEANS[n], inv = 1.f / STDEV[n];
  for (int i = tid; i < 8192; i += 256) pw[i >> 9][i & 511] = wv[i];
  if (tid < 128) {
    int pp = tid >> 4, j = tid & 15;
    int l = (pb * 8 + pp) * 8 + j;
    if (l > 511) l = 511;                       // replication pad
    pat[pp][j] = (xe[((size_t)b * 512 + l) * 21 + c] - mean) * inv;
  }
  __syncthreads();
  for (int i = tid; i < 4096; i += 256) {
    int pp = i >> 9, d = i & 511;
    int p = pb * 8 + pp;
    float s = PE[p * 512 + d];
#pragma unroll
    for (int j = 0; j < 16; j++) s += pat[pp][j] * pw[j][d];
    X[((size_t)n * 64 + p) * 512 + d] = f2bf(s);
  }
}

// ---------------------------------------------------------------- topk / softw
__global__ __launch_bounds__(64) void topk_kernel(
    const float* __restrict__ MC, int* __restrict__ TIDX) {
  __shared__ float g[64];
  int tau = threadIdx.x;
  float s = 0.f;
  for (int n = 0; n < 672; n++) s += MC[n * 64 + tau];
  g[tau] = s;
  __syncthreads();
  if (tau == 0) {
    for (int j = 0; j < 4; j++) {
      int best = 0; float bv = -1e30f;
      for (int t = 0; t < 64; t++) if (g[t] > bv) { bv = g[t]; best = t; }
      TIDX[j] = best;
      g[best] = -1e30f;
    }
  }
}

__global__ __launch_bounds__(256) void softw_kernel(
    const float* __restrict__ MC, const int* __restrict__ TIDX, float* __restrict__ WSM) {
  int n = blockIdx.x * 256 + threadIdx.x;
  if (n >= 672) return;
  float v[4], mx = -1e30f;
#pragma unroll
  for (int j = 0; j < 4; j++) { v[j] = MC[n * 64 + TIDX[j]]; mx = fmaxf(mx, v[j]); }
  float s = 0.f;
#pragma unroll
  for (int j = 0; j < 4; j++) { v[j] = __expf(v[j] - mx); s += v[j]; }
  float inv = 1.f / s;
#pragma unroll
  for (int j = 0; j < 4; j++) WSM[n * 4 + j] = v[j] * inv;
}

// agg[n,l,:] = sum_j w[n,j] * v[n,(l+delay_j)&63,:]   (V,OUT row-stride ld)
__global__ __launch_bounds__(256) void agg_kernel(
    const u16* __restrict__ V, int ld, const float* __restrict__ WSM,
    const int* __restrict__ TIDX, u16* __restrict__ OUT) {
  int n = blockIdx.x;
  __shared__ float w[4];
  __shared__ int dly[4];
  int tid = threadIdx.x;
  if (tid < 4) { w[tid] = WSM[n * 4 + tid]; dly[tid] = TIDX[tid]; }
  __syncthreads();
  for (int i = tid; i < 64 * 512; i += 256) {
    int l = i >> 9, d = i & 511;
    float s = 0.f;
#pragma unroll
    for (int j = 0; j < 4; j++)
      s += w[j] * bf2f(V[((size_t)n * 64 + ((l + dly[j]) & 63)) * ld + d]);
    OUT[((size_t)n * 64 + l) * ld + d] = f2bf(s);
  }
}

// ---------------------------------------------------------------- MFMA attention
// per (n,h): q,k,v 64x64 slices of QKV[43008][1536] (cols h*64 / 512+h*64 /
// 1024+h*64). scores = qk^T/8, softmax, out = P v -> overwrites q slice.
__global__ __launch_bounds__(256) void attn_mfma(u16* __restrict__ QKV) {
  __shared__ u16 lq[64][72], lk[64][72], lvt[64][72], lp[64][72];
  int n = blockIdx.x >> 3, h = blockIdx.x & 7;
  size_t base = (size_t)n * 64 * 1536;
  int qo = h * 64, ko = 512 + h * 64, vo = 1024 + h * 64;
  int tid = threadIdx.x, lane = tid & 63, w = tid >> 6;
  int r = tid >> 2, c0 = (tid & 3) * 16;
  *(u16x8*)&lq[r][c0]     = *(const u16x8*)&QKV[base + (size_t)r * 1536 + qo + c0];
  *(u16x8*)&lq[r][c0 + 8] = *(const u16x8*)&QKV[base + (size_t)r * 1536 + qo + c0 + 8];
  *(u16x8*)&lk[r][c0]     = *(const u16x8*)&QKV[base + (size_t)r * 1536 + ko + c0];
  *(u16x8*)&lk[r][c0 + 8] = *(const u16x8*)&QKV[base + (size_t)r * 1536 + ko + c0 + 8];
  u16x8 v0 = *(const u16x8*)&QKV[base + (size_t)r * 1536 + vo + c0];
  u16x8 v1 = *(const u16x8*)&QKV[base + (size_t)r * 1536 + vo + c0 + 8];
#pragma unroll
  for (int j = 0; j < 8; j++) { lvt[c0 + j][r] = v0[j]; lvt[c0 + 8 + j][r] = v1[j]; }
  __syncthreads();
  int m_in = lane & 15, ks = (lane >> 4) * 8;
  int rq = lane >> 4;   // row quad index
  s16x8 aq0 = *(const s16x8*)&lq[w * 16 + m_in][ks];
  s16x8 aq1 = *(const s16x8*)&lq[w * 16 + m_in][32 + ks];
  f32x4 s4[4];
#pragma unroll
  for (int nf = 0; nf < 4; nf++) {
    s4[nf] = (f32x4){0.f, 0.f, 0.f, 0.f};
    s16x8 b0 = *(const s16x8*)&lk[nf * 16 + m_in][ks];
    s16x8 b1 = *(const s16x8*)&lk[nf * 16 + m_in][32 + ks];
    s4[nf] = __builtin_amdgcn_mfma_f32_16x16x32_bf16(aq0, b0, s4[nf], 0, 0, 0);
    s4[nf] = __builtin_amdgcn_mfma_f32_16x16x32_bf16(aq1, b1, s4[nf], 0, 0, 0);
  }
  // row softmax: lane holds rows rq*4+r (r=0..3), cols nf*16 + m_in.
  float mx[4] = {-1e30f, -1e30f, -1e30f, -1e30f};
#pragma unroll
  for (int nf = 0; nf < 4; nf++)
#pragma unroll
    for (int r4 = 0; r4 < 4; r4++) {
      s4[nf][r4] *= 0.125f;
      mx[r4] = fmaxf(mx[r4], s4[nf][r4]);
    }
#pragma unroll
  for (int o = 1; o < 16; o <<= 1)
#pragma unroll
    for (int r4 = 0; r4 < 4; r4++) mx[r4] = fmaxf(mx[r4], __shfl_xor(mx[r4], o));
  float sum[4] = {0.f, 0.f, 0.f, 0.f};
#pragma unroll
  for (int nf = 0; nf < 4; nf++)
#pragma unroll
    for (int r4 = 0; r4 < 4; r4++) {
      float e = __expf(s4[nf][r4] - mx[r4]);
      s4[nf][r4] = e;
      sum[r4] += e;
    }
#pragma unroll
  for (int o = 1; o < 16; o <<= 1)
#pragma unroll
    for (int r4 = 0; r4 < 4; r4++) sum[r4] += __shfl_xor(sum[r4], o);
#pragma unroll
  for (int nf = 0; nf < 4; nf++)
#pragma unroll
    for (int r4 = 0; r4 < 4; r4++)
      lp[w * 16 + rq * 4 + r4][nf * 16 + m_in] = f2bf(s4[nf][r4] / sum[r4]);
  __syncthreads();
  // PV: out[m][d] = sum_s P[m][s] Vt[d][s]
  s16x8 ap0 = *(const s16x8*)&lp[w * 16 + m_in][ks];
  s16x8 ap1 = *(const s16x8*)&lp[w * 16 + m_in][32 + ks];
#pragma unroll
  for (int nf = 0; nf < 4; nf++) {
    f32x4 o4 = (f32x4){0.f, 0.f, 0.f, 0.f};
    s16x8 b0 = *(const s16x8*)&lvt[nf * 16 + m_in][ks];
    s16x8 b1 = *(const s16x8*)&lvt[nf * 16 + m_in][32 + ks];
    o4 = __builtin_amdgcn_mfma_f32_16x16x32_bf16(ap0, b0, o4, 0, 0, 0);
    o4 = __builtin_amdgcn_mfma_f32_16x16x32_bf16(ap1, b1, o4, 0, 0, 0);
#pragma unroll
    for (int r4 = 0; r4 < 4; r4++)
      QKV[base + (size_t)(w * 16 + rq * 4 + r4) * 1536 + qo + nf * 16 + m_in] =
          f2bf(o4[r4]);
  }
}

// ---------------------------------------------------------------- series decomp
// X <- (X + DELTA) - movavg_25_edge_replicated(X + DELTA); DELTA row-stride ds.
__global__ __launch_bounds__(256) void decomp_kernel(
    u16* __restrict__ X, const u16* __restrict__ DELTA, int ds) {
  int n = blockIdx.x >> 1;
  int d = ((blockIdx.x & 1) << 8) + threadIdx.x;
  size_t xb = ((size_t)n * 64) * 512 + d;
  size_t db = ((size_t)n * 64) * ds + d;
  float v[64];
#pragma unroll
  for (int l = 0; l < 64; l++)
    v[l] = bf2f(X[xb + (size_t)l * 512]) + bf2f(DELTA[db + (size_t)l * ds]);
  float s = 12.f * v[0];
#pragma unroll
  for (int t = 0; t <= 12; t++) s += v[t];
#pragma unroll
  for (int l = 0; l < 64; l++) {
    float out = v[l] - s * (1.f / 25.f);
    X[xb + (size_t)l * 512] = f2bf(out);
    if (l < 63) {
      int add = l + 13; if (add > 63) add = 63;
      int sub = l - 12; if (sub < 0) sub = 0;
      s += v[add] - v[sub];
    }
  }
}

// ---------------------------------------------------------------- batchnorm
__global__ __launch_bounds__(256) void bn_part(
    const u16* __restrict__ X, float* __restrict__ PS) {
  int ch = blockIdx.x, tid = threadIdx.x;
  float s1a = 0, s2a = 0, s1b = 0, s2b = 0;
  size_t base = (size_t)ch * 128 * 512;
  for (int r = 0; r < 128; r++) {
    float a = bf2f(X[base + (size_t)r * 512 + tid]);
    float b = bf2f(X[base + (size_t)r * 512 + tid + 256]);
    s1a += a; s2a += a * a; s1b += b; s2b += b * b;
  }
  PS[(size_t)(ch * 2 + 0) * 512 + tid] = s1a;
  PS[(size_t)(ch * 2 + 0) * 512 + tid + 256] = s1b;
  PS[(size_t)(ch * 2 + 1) * 512 + tid] = s2a;
  PS[(size_t)(ch * 2 + 1) * 512 + tid + 256] = s2b;
}

__global__ __launch_bounds__(256) void bn_final(
    const float* __restrict__ PS, const float* __restrict__ g,
    const float* __restrict__ b, float* __restrict__ SCALE, float* __restrict__ SHIFT) {
  int d = blockIdx.x * 256 + threadIdx.x;   // < 512
  float s = 0, ss = 0;
  for (int c = 0; c < 336; c++) {
    s += PS[(size_t)(c * 2) * 512 + d];
    ss += PS[(size_t)(c * 2 + 1) * 512 + d];
  }
  float mu = s * (1.f / 43008.f);
  float var = ss * (1.f / 43008.f) - mu * mu;
  float inv = 1.f / sqrtf(var + 1e-5f);
  float sc = g[d] * inv;
  SCALE[d] = sc;
  SHIFT[d] = b[d] - mu * sc;
}

// ---------------------------------------------------------------- bn transpose
// ENC[n][d*64+p] = bn(X[n][p][d]); LDS-tiled so both sides are coalesced.
__global__ __launch_bounds__(256) void bn_transpose_kernel(
    const u16* __restrict__ X, const float* __restrict__ SCALE,
    const float* __restrict__ SHIFT, u16* __restrict__ ENC) {
  __shared__ u16 t[64][72];
  int n = blockIdx.x >> 3, dc = (blockIdx.x & 7) * 64;
  int tid = threadIdx.x;
  for (int i = tid; i < 4096; i += 256) {
    int p = i >> 6, d = i & 63;
    float v = bf2f(X[((size_t)n * 64 + p) * 512 + dc + d]) * SCALE[dc + d] + SHIFT[dc + d];
    t[p][d] = f2bf(v);
  }
  __syncthreads();
  for (int i = tid; i < 4096; i += 256) {
    int d = i >> 6, p = i & 63;
    ENC[(size_t)n * 32768 + (size_t)(dc + d) * 64 + p] = t[p][d];
  }
}

// ---------------------------------------------------------------- head GEMM
// PART[kc][672][96] partial over 16 K-chunks; A = ENC (contiguous rows of 32768)
__global__ __launch_bounds__(256) void head_gemm(
    const u16* __restrict__ ENC, const u16* __restrict__ Wht,
    float* __restrict__ PART) {
  __shared__ u16 lA[64][40];
  __shared__ u16 lB[96][40];
  int bm = blockIdx.x;   // 0..10
  int kc = blockIdx.y;   // 0..15
  int tid = threadIdx.x, lane = tid & 63, w = tid >> 6;
  int sr = tid >> 2, sc0 = (tid & 3) * 8;
  f32x4 acc[6];
#pragma unroll
  for (int i = 0; i < 6; i++) acc[i] = (f32x4){0.f, 0.f, 0.f, 0.f};
  for (int kk0 = 0; kk0 < 2048; kk0 += 32) {
    int k0 = kc * 2048 + kk0;
    *(u16x8*)&lA[sr][sc0] =
        *(const u16x8*)&ENC[(size_t)(bm * 64 + sr) * 32768 + k0 + sc0];
    for (int i = tid; i < 96 * 4; i += 256) {
      int rB = i >> 2, seg = (i & 3) * 8;
      *(u16x8*)&lB[rB][seg] = *(const u16x8*)&Wht[(size_t)rB * 32768 + k0 + seg];
    }
    __syncthreads();
    int ar = w * 16 + (lane & 15);
    int kk = (lane >> 4) * 8;
    s16x8 af = *(const s16x8*)&lA[ar][kk];
#pragma unroll
    for (int nb = 0; nb < 6; nb++) {
      s16x8 bfr = *(const s16x8*)&lB[nb * 16 + (lane & 15)][kk];
      acc[nb] = __builtin_amdgcn_mfma_f32_16x16x32_bf16(af, bfr, acc[nb], 0, 0, 0);
    }
    __syncthreads();
  }
  int rb = bm * 64 + w * 16 + ((lane >> 4) << 2);
  int cl = lane & 15;
#pragma unroll
  for (int nb = 0; nb < 6; nb++) {
    int col = nb * 16 + cl;
#pragma unroll
    for (int r = 0; r < 4; r++) {
      int row = rb + r;
      if (row < 672) PART[((size_t)kc * 672 + row) * 96 + col] = acc[nb][r];
    }
  }
}

__global__ __launch_bounds__(256) void head_reduce(
    const float* __restrict__ PART, const float* __restrict__ bh,
    const float* __restrict__ STDEV, const float* __restrict__ MEANS,
    float* __restrict__ OUT) {
  int i = blockIdx.x * 256 + threadIdx.x;
  if (i >= 672 * 96) return;
  int n = i / 96, r = i % 96;
  float s = bh[r];
  for (int kc = 0; kc < 16; kc++) s += PART[((size_t)kc * 672 + n) * 96 + r];
  int b = n / 21, c = n % 21;
  OUT[((size_t)b * 96 + r) * 21 + c] = s * STDEV[n] + MEANS[n];
}

// ============================================================================
extern "C" void kernel_launch(void* const* d_in, const int* in_sizes, int n_in,
                              void* d_out, int out_size, void* d_ws, size_t ws_size,
                              hipStream_t stream) {
  const float* x_enc = (const float*)d_in[0];
  const float* w_val = (const float*)d_in[1];
  const float* Wq_ac = (const float*)d_in[2];
  const float* Wk_ac = (const float*)d_in[3];
  const float* Wv_ac = (const float*)d_in[4];
  const float* Wo_ac = (const float*)d_in[5];
  const float* bq_ac = (const float*)d_in[6];
  const float* bk_ac = (const float*)d_in[7];
  const float* bv_ac = (const float*)d_in[8];
  const float* bo_ac = (const float*)d_in[9];
  const float* Wq_sa = (const float*)d_in[10];
  const float* Wk_sa = (const float*)d_in[11];
  const float* Wv_sa = (const float*)d_in[12];
  const float* Wo_sa = (const float*)d_in[13];
  const float* bq_sa = (const float*)d_in[14];
  const float* bk_sa = (const float*)d_in[15];
  const float* bv_sa = (const float*)d_in[16];
  const float* bo_sa = (const float*)d_in[17];
  const float* WfW   = (const float*)d_in[18];
  const float* bfW   = (const float*)d_in[19];
  const float* W1    = (const float*)d_in[20];
  const float* W2    = (const float*)d_in[21];
  const float* bn_g  = (const float*)d_in[22];
  const float* bn_b  = (const float*)d_in[23];
  const float* W_head = (const float*)d_in[24];
  const float* b_head = (const float*)d_in[25];
  (void)in_sizes; (void)n_in; (void)out_size;

  // ---- workspace carve-up (~213 MB)
  char* wsp = (char*)d_ws;
  size_t off = 0;
  auto alloc = [&](size_t bytes) -> void* {
    void* p = wsp + off;
    off += (bytes + 255) & ~(size_t)255;
    return p;
  };
  u16* X    = (u16*)alloc((size_t)MROWS * 512 * 2);
  u16* Q3   = (u16*)alloc((size_t)MROWS * 1536 * 2);   // 3 column slices
  u16* WT   = (u16*)alloc((size_t)17301504 * 2);
  float* PE = (float*)alloc((size_t)32768 * 4);
  float* MEANS = (float*)alloc(672 * 4);
  float* STDEV = (float*)alloc(672 * 4);
  float* MC = (float*)alloc(672 * 64 * 4);
  int* TIDX = (int*)alloc(4 * 4);
  float* WSM = (float*)alloc(672 * 4 * 4);
  float* BNP = (float*)alloc((size_t)336 * 1024 * 4);
  float* SCALE = (float*)alloc(512 * 4);
  float* SHIFT = (float*)alloc(512 * 4);
  float* HEADP = (float*)alloc((size_t)16 * 672 * 96 * 4);
  // column-slice aliases (element offsets into rows of 1536)
  u16* C0 = Q3;          // cols    0..511
  u16* C1 = Q3 + 512;    // cols  512..1023
  u16* C2 = Q3 + 1024;   // cols 1024..1535
  // FFN scratch overlays Q3 (dead between decomp1 and decomp2):
  u16* HBUF = Q3;                                  // [10752][2048] = 44 MB
  u16* YBUF = Q3 + (size_t)2 * MROWS * 512;        // [43008][512]  = 44 MB
  u16* ENC  = Q3;                                  // head: [672][32768] = 44 MB

  if (off > ws_size) {
    zero_out_kernel<<<252, 256, 0, stream>>>((float*)d_out, 672 * 96);
    return;
  }

  // ---- weight prep: transpose + bf16 convert
  u16* wtp = WT;
  auto tp = [&](const float* src, int K, int N) -> const u16* {
    u16* dst = wtp;
    transpose_cvt<<<dim3(K / 32, N / 32), dim3(32, 8), 0, stream>>>(src, dst, K, N);
    wtp += (size_t)K * N;
    return dst;
  };
  struct LW {
    const u16 *qsa, *ksa, *vsa, *osa, *qac, *kac, *vac, *oac, *wf, *w1, *w2;
  } lw[3];
  for (int l = 0; l < 3; l++) {
    lw[l].qsa = tp(Wq_sa + (size_t)l * 262144, 512, 512);
    lw[l].ksa = tp(Wk_sa + (size_t)l * 262144, 512, 512);
    lw[l].vsa = tp(Wv_sa + (size_t)l * 262144, 512, 512);
    lw[l].osa = tp(Wo_sa + (size_t)l * 262144, 512, 512);
    lw[l].qac = tp(Wq_ac + (size_t)l * 262144, 512, 512);
    lw[l].kac = tp(Wk_ac + (size_t)l * 262144, 512, 512);
    lw[l].vac = tp(Wv_ac + (size_t)l * 262144, 512, 512);
    lw[l].oac = tp(Wo_ac + (size_t)l * 262144, 512, 512);
    lw[l].wf  = tp(WfW   + (size_t)l * 524288, 1024, 512);
    lw[l].w1  = tp(W1    + (size_t)l * 1048576, 512, 2048);
    lw[l].w2  = tp(W2    + (size_t)l * 1048576, 2048, 512);
  }
  const u16* wht = tp(W_head, 32768, 96);

  // plain gemm: C[M,N] = A@Bt^T + b0   (1D grid, n-inner)
  auto gemm = [&](const u16* A, int lda, const u16* Bt, int ldb, const float* b0,
                  u16* C, int ldc, int M, int N, int K, int relu) {
    int nb = N / 128;
    gemm128p<<<(M / 128) * nb, 256, 0, stream>>>(
        A, A, lda, K, Bt, ldb, b0, nullptr, nullptr, C, ldc, K, relu, nb);
  };

  // ---- front end
  instnorm_kernel<<<672, 256, 0, stream>>>(x_enc, MEANS, STDEV);
  pe_kernel<<<128, 256, 0, stream>>>(PE);
  patch_kernel<<<672 * 8, 256, 0, stream>>>(x_enc, w_val, PE, MEANS, STDEV, X);

  // ---- encoder layers
  for (int l = 0; l < 3; l++) {
    const LW& w = lw[l];
    // SA: fused QKV (N=1536) -> Q3 cols [q|k|v]
    gemm128p<<<336 * 12, 256, 0, stream>>>(
        X, X, 512, 512, w.qsa, 512,
        bq_sa + l * 512, bk_sa + l * 512, bv_sa + l * 512, Q3, 1536, 512, 0, 12);
    attn_mfma<<<5376, 256, 0, stream>>>(Q3);                      // out -> C0
    gemm(C0, 1536, w.osa, 512, bo_sa + l * 512, C1, 1536, MROWS, 512, 512, 0); // s->C1
    // AC branch
    gemm(X, 512, w.qac, 512, bq_ac + l * 512, C2, 1536, MROWS, 512, 512, 0);   // q->C2
    gemm(X, 512, w.kac, 512, bk_ac + l * 512, C0, 1536, MROWS, 512, 512, 0);   // k->C0
    gram_mc_kernel<<<672, 256, 0, stream>>>(C2, C0, 1536, MC);
    topk_kernel<<<1, 64, 0, stream>>>(MC, TIDX);
    softw_kernel<<<3, 256, 0, stream>>>(MC, TIDX, WSM);
    gemm(X, 512, w.vac, 512, bv_ac + l * 512, C2, 1536, MROWS, 512, 512, 0);   // v->C2
    agg_kernel<<<672, 256, 0, stream>>>(C2, 1536, WSM, TIDX, C0);              // ->C0
    gemm(C0, 1536, w.oac, 512, bo_ac + l * 512, C2, 1536, MROWS, 512, 512, 0); // a->C2
    // fused = cat(a, s) @ Wf + bf  (dual-A via ksplit) -> C0
    gemm128p<<<336 * 4, 256, 0, stream>>>(
        C2, C1, 1536, 512, w.wf, 1024,
        bfW + l * 512, nullptr, nullptr, C0, 1536, 1024, 0, 4);
    decomp_kernel<<<1344, 256, 0, stream>>>(X, C0, 1536);
    // FFN in 4 M-chunks (hidden HBUF=Q3 base, y -> YBUF)
    for (int c = 0; c < 4; c++) {
      const u16* Xc = X + (size_t)c * 10752 * 512;
      u16* Yc = YBUF + (size_t)c * 10752 * 512;
      gemm(Xc, 512, w.w1, 512, nullptr, HBUF, 2048, 10752, 2048, 512, 1);
      gemm(HBUF, 2048, w.w2, 2048, nullptr, Yc, 512, 10752, 512, 2048, 0);
    }
    decomp_kernel<<<1344, 256, 0, stream>>>(X, YBUF, 512);
  }

  // ---- batchnorm + head
  bn_part<<<336, 256, 0, stream>>>(X, BNP);
  bn_final<<<2, 256, 0, stream>>>(BNP, bn_g, bn_b, SCALE, SHIFT);
  bn_transpose_kernel<<<672 * 8, 256, 0, stream>>>(X, SCALE, SHIFT, ENC);
  head_gemm<<<dim3(11, 16), 256, 0, stream>>>(ENC, wht, HEADP);
  head_reduce<<<252, 256, 0, stream>>>(HEADP, b_head, STDEV, MEANS, (float*)d_out);
}